// Round 6
// baseline (358.575 us; speedup 1.0000x reference)
//
#include <hip/hip_runtime.h>
#include <stdint.h>

typedef unsigned short u16;
typedef __bf16  bf16x8 __attribute__((ext_vector_type(8), may_alias));
typedef u16     u16x8  __attribute__((ext_vector_type(8), may_alias));
typedef float   f32x4  __attribute__((ext_vector_type(4)));
typedef float   f32x4u __attribute__((ext_vector_type(4), may_alias));

#define Bv   2
#define Sv   2048
#define Dv   2048
#define Hv   16
#define KVHv 4
#define HDv  128
#define Tv   (Bv*Sv)      // 4096 tokens
#define QKVN 3072         // 2048 Q + 512 K + 512 V
#define MAXROWS 4224      // 33 tiles of 128 (worst-case padded segments)

__device__ __forceinline__ float b2f(u16 u) {
    union { float f; uint32_t i; } x; x.i = ((uint32_t)u) << 16; return x.f;
}
__device__ __forceinline__ u16 f2b(float f) {
    union { float f; uint32_t u; } x; x.f = f;
    uint32_t r = x.u + 0x7fff + ((x.u >> 16) & 1);
    return (u16)(r >> 16);
}
// global -> LDS direct (16B per lane; LDS dest wave-uniform base, HW adds lane*16)
__device__ __forceinline__ void gload_lds16(const void* g, void* l) {
    __builtin_amdgcn_global_load_lds((__attribute__((address_space(1))) void*)(uintptr_t)g,
                                     (__attribute__((address_space(3))) void*)(uintptr_t)l,
                                     16, 0, 0);
}

// ---------- stable modality compaction: fwd[t]=compact pos, inv[pos]=t (or -1 pad) ----------
__global__ __launch_bounds__(1024) void scan_mod(const int* __restrict__ mod, int* __restrict__ fwd,
                                                 int* __restrict__ inv, int* __restrict__ hdr) {
    __shared__ int cnt[1024];
    const int tid = threadIdx.x;
    int m[4]; int c = 0;
#pragma unroll
    for (int e = 0; e < 4; ++e) { m[e] = mod[tid * 4 + e]; c += (m[e] == 0); }
    cnt[tid] = c;
    __syncthreads();
    for (int off = 1; off < 1024; off <<= 1) {
        int v = (tid >= off) ? cnt[tid - off] : 0;
        __syncthreads();
        cnt[tid] += v;
        __syncthreads();
    }
    const int c0 = cnt[1023];
    const int c0pad = (c0 + 127) & ~127;
    const int c1 = Tv - c0;
    const int total = c0pad + ((c1 + 127) & ~127);
    for (int p = tid; p < MAXROWS; p += 1024) inv[p] = -1;
    __syncthreads();
    const int ex0 = cnt[tid] - c;            // mod-0 tokens before this chunk
    int z = 0;
#pragma unroll
    for (int e = 0; e < 4; ++e) {
        int t = tid * 4 + e;
        int pos;
        if (m[e] == 0) { pos = ex0 + z; ++z; }
        else           { pos = c0pad + (t - (ex0 + z)); }
        fwd[t] = pos;
        inv[pos] = t;
    }
    if (tid == 0) { hdr[0] = total >> 7; hdr[1] = c0pad; hdr[2] = total; }
}

// ---------- gather + cast: Xg[pos] = bf16(x[inv[pos]]) or 0 ----------
__global__ void gather_cast(const float* __restrict__ x, const int* __restrict__ inv,
                            u16* __restrict__ Xg) {
    int v = blockIdx.x * 256 + threadIdx.x;
    int pos = v >> 8, c8 = (v & 255) * 8;
    int t = inv[pos];
    u16x8 val = {0, 0, 0, 0, 0, 0, 0, 0};
    if (t >= 0) {
        f32x4u a = *(const f32x4u*)&x[(size_t)t * Dv + c8];
        f32x4u b = *(const f32x4u*)&x[(size_t)t * Dv + c8 + 4];
#pragma unroll
        for (int j = 0; j < 4; ++j) { val[j] = f2b(a[j]); val[4 + j] = f2b(b[j]); }
    }
    *(u16x8*)&Xg[(size_t)pos * Dv + c8] = val;
}

// ---------- transpose + cast f32->bf16, batched over modality (blockIdx.z) ----------
__global__ void transpose_cast(const float* __restrict__ in, u16* __restrict__ out, int C,
                               size_t inZ, size_t outZ) {
    in  += (size_t)blockIdx.z * inZ;
    out += (size_t)blockIdx.z * outZ;
    __shared__ u16 tile[64][72];
    const int tr = blockIdx.y * 64, tc = blockIdx.x * 64;
    const int tid = threadIdx.x;
#pragma unroll
    for (int i = 0; i < 4; ++i) {
        int s = tid + 256 * i;
        int r = s >> 4, c4 = (s & 15) * 4;
        f32x4u v = *(const f32x4u*)&in[(size_t)(tr + r) * C + tc + c4];
#pragma unroll
        for (int j = 0; j < 4; ++j) tile[r][c4 + j] = f2b(v[j]);
    }
    __syncthreads();
#pragma unroll
    for (int i = 0; i < 2; ++i) {
        int s = tid + 256 * i;
        int r = s >> 3, c8 = (s & 7) * 8;
        u16x8 v;
#pragma unroll
        for (int j = 0; j < 8; ++j) v[j] = tile[c8 + j][r];
        *(u16x8*)&out[(size_t)(tc + r) * 2048 + tr + c8] = v;
    }
}

// ---------- segmented GEMM: C[inv[row]] = A(total x 2048) * Wt_seg(Nfull x 2048)^T ----------
template <typename OutT>
__global__ __launch_bounds__(256) void gemm_seg(const u16* __restrict__ A,
                                                const u16* __restrict__ Bt,
                                                OutT* __restrict__ C,
                                                const int* __restrict__ inv,
                                                const int* __restrict__ hdr,
                                                int Nfull, int ldC) {
    const int total = hdr[2], c0pad = hdr[1];
    const int bm = blockIdx.y * 128;
    if (bm >= total) return;
    const u16* B = Bt + (size_t)((bm >= c0pad) ? 1 : 0) * Nfull * 2048;
    const int bn = blockIdx.x * 128;
    const int tid = threadIdx.x;
    const int wave = tid >> 6, lane = tid & 63;
    const int l15 = lane & 15, l4 = lane >> 4;
    const int wr = (wave >> 1) * 64, wc = (wave & 1) * 64;
    __shared__ u16 lA[2][128 * 64];
    __shared__ u16 lB[2][128 * 64];
    f32x4 acc[4][4] = {};
    auto STAGE = [&](int kt, int buf) {
#pragma unroll
        for (int i = 0; i < 4; ++i) {
            int s_u = wave * 64 + 256 * i;
            int s = s_u + lane;
            int r = s >> 3, k8 = (s & 7) * 8;
            gload_lds16(A + (size_t)(bm + r) * 2048 + kt * 64 + k8, &lA[buf][(size_t)s_u * 8]);
            gload_lds16(B + (size_t)(bn + r) * 2048 + kt * 64 + k8, &lB[buf][(size_t)s_u * 8]);
        }
    };
    STAGE(0, 0);
    __syncthreads();
    for (int kt = 0; kt < 32; ++kt) {
        const int cur = kt & 1;
        if (kt < 31) STAGE(kt + 1, cur ^ 1);
#pragma unroll
        for (int kc = 0; kc < 2; ++kc) {
            bf16x8 af[4], bfr[4];
#pragma unroll
            for (int i = 0; i < 4; ++i)
                af[i] = *(const bf16x8*)&lA[cur][(wr + i * 16 + l15) * 64 + kc * 32 + l4 * 8];
#pragma unroll
            for (int j = 0; j < 4; ++j)
                bfr[j] = *(const bf16x8*)&lB[cur][(wc + j * 16 + l15) * 64 + kc * 32 + l4 * 8];
#pragma unroll
            for (int i = 0; i < 4; ++i)
#pragma unroll
                for (int j = 0; j < 4; ++j)
                    acc[i][j] = __builtin_amdgcn_mfma_f32_16x16x32_bf16(af[i], bfr[j], acc[i][j], 0, 0, 0);
        }
        __syncthreads();
    }
    int tok[4][4];
#pragma unroll
    for (int i = 0; i < 4; ++i)
#pragma unroll
        for (int r = 0; r < 4; ++r)
            tok[i][r] = inv[bm + wr + i * 16 + l4 * 4 + r];
#pragma unroll
    for (int i = 0; i < 4; ++i)
#pragma unroll
        for (int j = 0; j < 4; ++j) {
            int col = bn + wc + j * 16 + l15;
#pragma unroll
            for (int r = 0; r < 4; ++r)
                if (tok[i][r] >= 0) {
                    if constexpr (sizeof(OutT) == 2) C[(size_t)tok[i][r] * ldC + col] = f2b(acc[i][j][r]);
                    else                             C[(size_t)tok[i][r] * ldC + col] = acc[i][j][r];
                }
        }
}

// ---------- RoPE in place on Q,K halves of QKV (bf16); freq_cis f32; folds 1/sqrt(HD) into Q ----------
__global__ void rope_kernel(u16* __restrict__ QKV, const float* __restrict__ fc) {
    int p = blockIdx.x * 256 + threadIdx.x;
    const int t = p / 1280;
    const int r = p - t * 1280;
    const int s = t & (Sv - 1);
    int col, d2; float scale;
    if (r < 1024) { col = 2 * r;                d2 = r & 63;  scale = 0.08838834764831845f; }
    else          { int rr = r - 1024; col = 2048 + 2 * rr; d2 = rr & 63; scale = 1.0f; }
    u16* ptr = QKV + (size_t)t * QKVN + col;
    float t0 = b2f(ptr[0]), t1 = b2f(ptr[1]);
    f32x4u f = *(const f32x4u*)&fc[((size_t)s * 64 + d2) * 4];   // [c, -s, s, c]
    ptr[0] = f2b((t0 * f[0] + t1 * f[1]) * scale);
    ptr[1] = f2b((t0 * f[2] + t1 * f[3]) * scale);
}

// ---------- causal GQA flash attention (paired q-tiles) ----------
// LDS = 64KB (Kb dbuf 32K + Vb single 16K + Pl 16K) -> 2 blocks/CU resident.
// K: double-buffered via global_load_lds (prefetch j+1 at iter start).
// V: single-buffered, reg-staged T14 (issue loads early, ds_write after post-compute barrier).
// Output written COMPACT: row fwd[token], ready as the out-proj GEMM A-operand.
__global__ __launch_bounds__(512) void attn_fwd(const u16* __restrict__ QKV, u16* __restrict__ Ag,
                                                const int* __restrict__ fwd) {
    const int p = blockIdx.x;                 // pair id 0..15
    const int h = blockIdx.y, b = blockIdx.z;
    const int kvh = h >> 2;
    const int tid = threadIdx.x, wave = tid >> 6, lane = tid & 63;
    const int wgrp = wave >> 2, wl = wave & 3;
    const int l15 = lane & 15, l4 = lane >> 4;
    const int myqb = wgrp ? (31 - p) : p;     // this wave-group's q-tile
    __shared__ u16 Kb[2][64 * 128];
    __shared__ u16 Vb[128 * 64];
    __shared__ u16 Pl[8][16 * 64];

    bf16x8 qf[4];
    {
        const size_t qrow = (size_t)(b * Sv + myqb * 64 + wl * 16 + l15);
#pragma unroll
        for (int kc = 0; kc < 4; ++kc)
            qf[kc] = *(const bf16x8*)&QKV[qrow * QKVN + h * 128 + kc * 32 + l4 * 8];
    }
    f32x4 oacc[8] = {};
    float mrow[4] = {-1e30f, -1e30f, -1e30f, -1e30f};
    float lrow[4] = {0.f, 0.f, 0.f, 0.f};

    const size_t kvbase = (size_t)b * Sv * QKVN + 2048 + kvh * 128;

    // ---- prologue: stage tile 0 (K into Kb[0], V into Vb) ----
    {
#pragma unroll
        for (int i = 0; i < 2; ++i) {
            int s_u = wave * 64 + 512 * i;
            int s = s_u + lane;
            int r = s >> 4;
            int cs = (s & 15) ^ (r & 7);
            gload_lds16(QKV + kvbase + (size_t)r * QKVN + cs * 8, &Kb[0][(size_t)s_u * 8]);
        }
        u16x8 vr0 = *(const u16x8*)&QKV[kvbase + 512 + (size_t)lane * QKVN + (0 * 8 + wave) * 8];
        u16x8 vr1 = *(const u16x8*)&QKV[kvbase + 512 + (size_t)lane * QKVN + (1 * 8 + wave) * 8];
#pragma unroll
        for (int jj = 0; jj < 8; ++jj) {
            int d0 = wave * 8 + jj, d1 = (8 + wave) * 8 + jj;
            Vb[d0 * 64 + ((((lane >> 3) ^ jj) << 3) | (lane & 7))] = vr0[jj];
            Vb[d1 * 64 + ((((lane >> 3) ^ jj) << 3) | (lane & 7))] = vr1[jj];
        }
    }
    __syncthreads();

    for (int j = 0; j < 32; ++j) {
        const int cur = j & 1;
        const bool stage_next = (j < 31);
        u16x8 vn0, vn1;
        // ---- issue next tile's loads (K async to other LDS buf; V to regs) ----
        if (stage_next) {
            const size_t nb = kvbase + (size_t)(j + 1) * 64 * QKVN;
#pragma unroll
            for (int i = 0; i < 2; ++i) {
                int s_u = wave * 64 + 512 * i;
                int s = s_u + lane;
                int r = s >> 4;
                int cs = (s & 15) ^ (r & 7);
                gload_lds16(QKV + nb + (size_t)r * QKVN + cs * 8, &Kb[cur ^ 1][(size_t)s_u * 8]);
            }
            vn0 = *(const u16x8*)&QKV[nb + 512 + (size_t)lane * QKVN + (0 * 8 + wave) * 8];
            vn1 = *(const u16x8*)&QKV[nb + 512 + (size_t)lane * QKVN + (1 * 8 + wave) * 8];
        }
        // ---- compute on current K buffer + Vb ----
        if (j <= myqb) {
            f32x4 sacc[4] = {};
            __builtin_amdgcn_s_setprio(1);
#pragma unroll
            for (int kc = 0; kc < 4; ++kc)
#pragma unroll
                for (int nt = 0; nt < 4; ++nt) {
                    int cs = ((kc * 4 + l4) ^ (l15 & 7));
                    bf16x8 kf = *(const bf16x8*)&Kb[cur][(nt * 16 + l15) * 128 + cs * 8];
                    sacc[nt] = __builtin_amdgcn_mfma_f32_16x16x32_bf16(qf[kc], kf, sacc[nt], 0, 0, 0);
                }
            __builtin_amdgcn_s_setprio(0);
            if (j == myqb) {
#pragma unroll
                for (int nt = 0; nt < 4; ++nt)
#pragma unroll
                    for (int r = 0; r < 4; ++r)
                        if (nt * 16 + l15 > wl * 16 + l4 * 4 + r)
                            sacc[nt][r] = -1e30f;
            }
#pragma unroll
            for (int r = 0; r < 4; ++r) {
                float mx = fmaxf(fmaxf(sacc[0][r], sacc[1][r]), fmaxf(sacc[2][r], sacc[3][r]));
#pragma unroll
                for (int d = 1; d < 16; d <<= 1) mx = fmaxf(mx, __shfl_xor(mx, d, 64));
                float mnew = fmaxf(mrow[r], mx);
                float fs = __expf(mrow[r] - mnew);
                mrow[r] = mnew;
                float ps = 0.f;
#pragma unroll
                for (int nt = 0; nt < 4; ++nt) {
                    float pe = __expf(sacc[nt][r] - mnew);
                    sacc[nt][r] = pe;
                    ps += pe;
                }
#pragma unroll
                for (int d = 1; d < 16; d <<= 1) ps += __shfl_xor(ps, d, 64);
                lrow[r] = lrow[r] * fs + ps;
#pragma unroll
                for (int nt = 0; nt < 8; ++nt) oacc[nt][r] *= fs;
            }
#pragma unroll
            for (int nt = 0; nt < 4; ++nt)
#pragma unroll
                for (int r = 0; r < 4; ++r) {
                    int qrow = l4 * 4 + r;
                    int k = nt * 16 + l15;
                    Pl[wave][qrow * 64 + ((((k >> 3) ^ (qrow & 7)) << 3) | (k & 7))] = f2b(sacc[nt][r]);
                }
            bf16x8 pf0 = *(const bf16x8*)&Pl[wave][l15 * 64 + ((l4 ^ (l15 & 7)) << 3)];
            bf16x8 pf1 = *(const bf16x8*)&Pl[wave][l15 * 64 + (((4 + l4) ^ (l15 & 7)) << 3)];
            __builtin_amdgcn_s_setprio(1);
#pragma unroll
            for (int nt = 0; nt < 8; ++nt) {
                int d = nt * 16 + l15;           // d&7 == l15&7
                bf16x8 v0 = *(const bf16x8*)&Vb[d * 64 + ((l4 ^ (l15 & 7)) << 3)];
                bf16x8 v1 = *(const bf16x8*)&Vb[d * 64 + (((4 + l4) ^ (l15 & 7)) << 3)];
                oacc[nt] = __builtin_amdgcn_mfma_f32_16x16x32_bf16(pf0, v0, oacc[nt], 0, 0, 0);
                oacc[nt] = __builtin_amdgcn_mfma_f32_16x16x32_bf16(pf1, v1, oacc[nt], 0, 0, 0);
            }
            __builtin_amdgcn_s_setprio(0);
        }
        __syncthreads();   // all waves done reading Vb (and Kb[cur])
        // ---- late half of V stage: write regs into the (single) V buffer ----
        if (stage_next) {
#pragma unroll
            for (int jj = 0; jj < 8; ++jj) {
                int d0 = wave * 8 + jj, d1 = (8 + wave) * 8 + jj;
                Vb[d0 * 64 + ((((lane >> 3) ^ jj) << 3) | (lane & 7))] = vn0[jj];
                Vb[d1 * 64 + ((((lane >> 3) ^ jj) << 3) | (lane & 7))] = vn1[jj];
            }
        }
        __syncthreads();   // V writes visible; K gloads (vmcnt) drained for next iter
    }
    int rowmap[4];
#pragma unroll
    for (int r = 0; r < 4; ++r)
        rowmap[r] = fwd[b * Sv + myqb * 64 + wl * 16 + l4 * 4 + r];
#pragma unroll
    for (int nt = 0; nt < 8; ++nt)
#pragma unroll
        for (int r = 0; r < 4; ++r)
            Ag[(size_t)rowmap[r] * 2048 + h * 128 + nt * 16 + l15] = f2b(oacc[nt][r] / lrow[r]);
}

extern "C" void kernel_launch(void* const* d_in, const int* in_sizes, int n_in,
                              void* d_out, int out_size, void* d_ws, size_t ws_size,
                              hipStream_t stream) {
    const float* x   = (const float*)d_in[0];
    const float* fc  = (const float*)d_in[1];
    const int*   mod = (const int*)d_in[2];
    const float* wq  = (const float*)d_in[3];
    const float* wk  = (const float*)d_in[4];
    const float* wv  = (const float*)d_in[5];
    const float* wo  = (const float*)d_in[6];
    float* out = (float*)d_out;
    char* ws = (char*)d_ws;
    u16* Wqkv_t = (u16*)(ws);               // 2 x (3072 x 2048) bf16 = 25,165,824
    u16* Wo_t   = (u16*)(ws + 25165824);    // 2 x (2048 x 2048) bf16 = 16,777,216
    u16* Xg     = (u16*)(ws + 41943040);    // MAXROWS x 2048 bf16 = 17,301,504 (reused as Ag)
    u16* QKV    = (u16*)(ws + 59244544);    // 4096 x 3072 bf16 = 25,165,824
    int* fwd    = (int*)(ws + 84410368);    // 4096 ints
    int* inv    = (int*)(ws + 84426752);    // MAXROWS ints (+pad)
    int* hdr    = (int*)(ws + 84444160);    // small header
    u16* Ag     = Xg;                        // Xg dead after QKV GEMM

    transpose_cast<<<dim3(32, 32, 2), 256, 0, stream>>>(wq, Wqkv_t, 2048,
        (size_t)2048 * 2048, (size_t)3072 * 2048);
    transpose_cast<<<dim3(8, 32, 2),  256, 0, stream>>>(wk, Wqkv_t + (size_t)2048 * 2048, 512,
        (size_t)2048 * 512,  (size_t)3072 * 2048);
    transpose_cast<<<dim3(8, 32, 2),  256, 0, stream>>>(wv, Wqkv_t + (size_t)2560 * 2048, 512,
        (size_t)2048 * 512,  (size_t)3072 * 2048);
    transpose_cast<<<dim3(32, 32, 2), 256, 0, stream>>>(wo, Wo_t, 2048,
        (size_t)2048 * 2048, (size_t)2048 * 2048);
    scan_mod<<<1, 1024, 0, stream>>>(mod, fwd, inv, hdr);
    gather_cast<<<MAXROWS, 256, 0, stream>>>(x, inv, Xg);
    gemm_seg<u16><<<dim3(24, 33), 256, 0, stream>>>(Xg, Wqkv_t, QKV, inv, hdr, 3072, 3072);
    rope_kernel<<<20480, 256, 0, stream>>>(QKV, fc);
    attn_fwd<<<dim3(16, 16, 2), 512, 0, stream>>>(QKV, Ag, fwd);
    gemm_seg<float><<<dim3(16, 33), 256, 0, stream>>>(Ag, Wo_t, out, inv, hdr, 2048, 2048);
}

// Round 7
// 357.763 us; speedup vs baseline: 1.0023x; 1.0023x over previous
//
#include <hip/hip_runtime.h>
#include <stdint.h>

typedef unsigned short u16;
typedef __bf16  bf16x8 __attribute__((ext_vector_type(8), may_alias));
typedef u16     u16x8  __attribute__((ext_vector_type(8), may_alias));
typedef float   f32x4  __attribute__((ext_vector_type(4)));
typedef float   f32x4u __attribute__((ext_vector_type(4), may_alias));

#define Bv   2
#define Sv   2048
#define Dv   2048
#define Hv   16
#define KVHv 4
#define HDv  128
#define Tv   (Bv*Sv)      // 4096 tokens
#define QKVN 3072         // 2048 Q + 512 K + 512 V
#define MAXROWS 4224      // 33 tiles of 128 (worst-case padded segments)

__device__ __forceinline__ float b2f(u16 u) {
    union { float f; uint32_t i; } x; x.i = ((uint32_t)u) << 16; return x.f;
}
__device__ __forceinline__ u16 f2b(float f) {
    union { float f; uint32_t u; } x; x.f = f;
    uint32_t r = x.u + 0x7fff + ((x.u >> 16) & 1);
    return (u16)(r >> 16);
}
// global -> LDS direct (16B per lane; LDS dest wave-uniform base, HW adds lane*16)
__device__ __forceinline__ void gload_lds16(const void* g, void* l) {
    __builtin_amdgcn_global_load_lds((__attribute__((address_space(1))) void*)(uintptr_t)g,
                                     (__attribute__((address_space(3))) void*)(uintptr_t)l,
                                     16, 0, 0);
}

// ---------- stable modality compaction: fwd[t]=compact pos, inv[pos]=t (or -1 pad) ----------
__global__ __launch_bounds__(1024) void scan_mod(const int* __restrict__ mod, int* __restrict__ fwd,
                                                 int* __restrict__ inv, int* __restrict__ hdr) {
    __shared__ int cnt[1024];
    const int tid = threadIdx.x;
    int m[4]; int c = 0;
#pragma unroll
    for (int e = 0; e < 4; ++e) { m[e] = mod[tid * 4 + e]; c += (m[e] == 0); }
    cnt[tid] = c;
    __syncthreads();
    for (int off = 1; off < 1024; off <<= 1) {
        int v = (tid >= off) ? cnt[tid - off] : 0;
        __syncthreads();
        cnt[tid] += v;
        __syncthreads();
    }
    const int c0 = cnt[1023];
    const int c0pad = (c0 + 127) & ~127;
    const int c1 = Tv - c0;
    const int total = c0pad + ((c1 + 127) & ~127);
    for (int p = tid; p < MAXROWS; p += 1024) inv[p] = -1;
    __syncthreads();
    const int ex0 = cnt[tid] - c;            // mod-0 tokens before this chunk
    int z = 0;
#pragma unroll
    for (int e = 0; e < 4; ++e) {
        int t = tid * 4 + e;
        int pos;
        if (m[e] == 0) { pos = ex0 + z; ++z; }
        else           { pos = c0pad + (t - (ex0 + z)); }
        fwd[t] = pos;
        inv[pos] = t;
    }
    if (tid == 0) { hdr[0] = total >> 7; hdr[1] = c0pad; hdr[2] = total; }
}

// ---------- gather + cast: Xg[pos] = bf16(x[inv[pos]]) or 0 ----------
__global__ void gather_cast(const float* __restrict__ x, const int* __restrict__ inv,
                            u16* __restrict__ Xg) {
    int v = blockIdx.x * 256 + threadIdx.x;
    int pos = v >> 8, c8 = (v & 255) * 8;
    int t = inv[pos];
    u16x8 val = {0, 0, 0, 0, 0, 0, 0, 0};
    if (t >= 0) {
        f32x4u a = *(const f32x4u*)&x[(size_t)t * Dv + c8];
        f32x4u b = *(const f32x4u*)&x[(size_t)t * Dv + c8 + 4];
#pragma unroll
        for (int j = 0; j < 4; ++j) { val[j] = f2b(a[j]); val[4 + j] = f2b(b[j]); }
    }
    *(u16x8*)&Xg[(size_t)pos * Dv + c8] = val;
}

// ---------- gather rows (bf16): Ag[pos] = O[inv[pos]] or 0 ----------
__global__ void gather_rows(const u16* __restrict__ O, const int* __restrict__ inv,
                            u16* __restrict__ Ag) {
    int pos = blockIdx.x;
    int c8 = threadIdx.x * 8;
    int t = inv[pos];
    u16x8 val = {0, 0, 0, 0, 0, 0, 0, 0};
    if (t >= 0) val = *(const u16x8*)&O[(size_t)t * 2048 + c8];
    *(u16x8*)&Ag[(size_t)pos * 2048 + c8] = val;
}

// ---------- transpose + cast f32->bf16, batched over modality (blockIdx.z) ----------
__global__ void transpose_cast(const float* __restrict__ in, u16* __restrict__ out, int C,
                               size_t inZ, size_t outZ) {
    in  += (size_t)blockIdx.z * inZ;
    out += (size_t)blockIdx.z * outZ;
    __shared__ u16 tile[64][72];
    const int tr = blockIdx.y * 64, tc = blockIdx.x * 64;
    const int tid = threadIdx.x;
#pragma unroll
    for (int i = 0; i < 4; ++i) {
        int s = tid + 256 * i;
        int r = s >> 4, c4 = (s & 15) * 4;
        f32x4u v = *(const f32x4u*)&in[(size_t)(tr + r) * C + tc + c4];
#pragma unroll
        for (int j = 0; j < 4; ++j) tile[r][c4 + j] = f2b(v[j]);
    }
    __syncthreads();
#pragma unroll
    for (int i = 0; i < 2; ++i) {
        int s = tid + 256 * i;
        int r = s >> 3, c8 = (s & 7) * 8;
        u16x8 v;
#pragma unroll
        for (int j = 0; j < 8; ++j) v[j] = tile[c8 + j][r];
        *(u16x8*)&out[(size_t)(tc + r) * 2048 + tr + c8] = v;
    }
}

// ---------- segmented GEMM: C[inv[row]] = A(total x 2048) * Wt_seg(Nfull x 2048)^T ----------
template <typename OutT>
__global__ __launch_bounds__(256) void gemm_seg(const u16* __restrict__ A,
                                                const u16* __restrict__ Bt,
                                                OutT* __restrict__ C,
                                                const int* __restrict__ inv,
                                                const int* __restrict__ hdr,
                                                int Nfull, int ldC) {
    const int total = hdr[2], c0pad = hdr[1];
    const int bm = blockIdx.y * 128;
    if (bm >= total) return;
    const u16* B = Bt + (size_t)((bm >= c0pad) ? 1 : 0) * Nfull * 2048;
    const int bn = blockIdx.x * 128;
    const int tid = threadIdx.x;
    const int wave = tid >> 6, lane = tid & 63;
    const int l15 = lane & 15, l4 = lane >> 4;
    const int wr = (wave >> 1) * 64, wc = (wave & 1) * 64;
    __shared__ u16 lA[2][128 * 64];
    __shared__ u16 lB[2][128 * 64];
    f32x4 acc[4][4] = {};
    auto STAGE = [&](int kt, int buf) {
#pragma unroll
        for (int i = 0; i < 4; ++i) {
            int s_u = wave * 64 + 256 * i;
            int s = s_u + lane;
            int r = s >> 3, k8 = (s & 7) * 8;
            gload_lds16(A + (size_t)(bm + r) * 2048 + kt * 64 + k8, &lA[buf][(size_t)s_u * 8]);
            gload_lds16(B + (size_t)(bn + r) * 2048 + kt * 64 + k8, &lB[buf][(size_t)s_u * 8]);
        }
    };
    STAGE(0, 0);
    __syncthreads();
    for (int kt = 0; kt < 32; ++kt) {
        const int cur = kt & 1;
        if (kt < 31) STAGE(kt + 1, cur ^ 1);
#pragma unroll
        for (int kc = 0; kc < 2; ++kc) {
            bf16x8 af[4], bfr[4];
#pragma unroll
            for (int i = 0; i < 4; ++i)
                af[i] = *(const bf16x8*)&lA[cur][(wr + i * 16 + l15) * 64 + kc * 32 + l4 * 8];
#pragma unroll
            for (int j = 0; j < 4; ++j)
                bfr[j] = *(const bf16x8*)&lB[cur][(wc + j * 16 + l15) * 64 + kc * 32 + l4 * 8];
#pragma unroll
            for (int i = 0; i < 4; ++i)
#pragma unroll
                for (int j = 0; j < 4; ++j)
                    acc[i][j] = __builtin_amdgcn_mfma_f32_16x16x32_bf16(af[i], bfr[j], acc[i][j], 0, 0, 0);
        }
        __syncthreads();
    }
    int tok[4][4];
#pragma unroll
    for (int i = 0; i < 4; ++i)
#pragma unroll
        for (int r = 0; r < 4; ++r)
            tok[i][r] = inv[bm + wr + i * 16 + l4 * 4 + r];
#pragma unroll
    for (int i = 0; i < 4; ++i)
#pragma unroll
        for (int j = 0; j < 4; ++j) {
            int col = bn + wc + j * 16 + l15;
#pragma unroll
            for (int r = 0; r < 4; ++r)
                if (tok[i][r] >= 0) {
                    if constexpr (sizeof(OutT) == 2) C[(size_t)tok[i][r] * ldC + col] = f2b(acc[i][j][r]);
                    else                             C[(size_t)tok[i][r] * ldC + col] = acc[i][j][r];
                }
        }
}

// ---------- RoPE in place on Q,K halves of QKV (bf16); freq_cis f32; folds 1/sqrt(HD) into Q ----------
__global__ void rope_kernel(u16* __restrict__ QKV, const float* __restrict__ fc) {
    int p = blockIdx.x * 256 + threadIdx.x;
    const int t = p / 1280;
    const int r = p - t * 1280;
    const int s = t & (Sv - 1);
    int col, d2; float scale;
    if (r < 1024) { col = 2 * r;                d2 = r & 63;  scale = 0.08838834764831845f; }
    else          { int rr = r - 1024; col = 2048 + 2 * rr; d2 = rr & 63; scale = 1.0f; }
    u16* ptr = QKV + (size_t)t * QKVN + col;
    float t0 = b2f(ptr[0]), t1 = b2f(ptr[1]);
    f32x4u f = *(const f32x4u*)&fc[((size_t)s * 64 + d2) * 4];   // [c, -s, s, c]
    ptr[0] = f2b((t0 * f[0] + t1 * f[1]) * scale);
    ptr[1] = f2b((t0 * f[2] + t1 * f[3]) * scale);
}

// ---------- causal GQA flash attention (paired q-tiles, 2-phase K/V pipeline) ----------
// R4-exact structure: Kb[2]+Vb[2] (80KB), one barrier per iteration, DIRECT token-major output.
__global__ __launch_bounds__(512) void attn_fwd(const u16* __restrict__ QKV, u16* __restrict__ O) {
    const int p = blockIdx.x;                 // pair id 0..15
    const int h = blockIdx.y, b = blockIdx.z;
    const int kvh = h >> 2;
    const int tid = threadIdx.x, wave = tid >> 6, lane = tid & 63;
    const int wgrp = wave >> 2, wl = wave & 3;
    const int l15 = lane & 15, l4 = lane >> 4;
    const int myqb = wgrp ? (31 - p) : p;     // this wave-group's q-tile
    __shared__ u16 Kb[2][64 * 128];
    __shared__ u16 Vb[2][128 * 64];
    __shared__ u16 Pl[8][16 * 64];

    bf16x8 qf[4];
    {
        const size_t qrow = (size_t)(b * Sv + myqb * 64 + wl * 16 + l15);
#pragma unroll
        for (int kc = 0; kc < 4; ++kc)
            qf[kc] = *(const bf16x8*)&QKV[qrow * QKVN + h * 128 + kc * 32 + l4 * 8];
    }
    f32x4 oacc[8] = {};
    float mrow[4] = {-1e30f, -1e30f, -1e30f, -1e30f};
    float lrow[4] = {0.f, 0.f, 0.f, 0.f};

    const size_t kvbase = (size_t)b * Sv * QKVN + 2048 + kvh * 128;

    // ---- prologue: stage tile 0 into buffer 0 ----
    {
#pragma unroll
        for (int i = 0; i < 2; ++i) {
            int s_u = wave * 64 + 512 * i;
            int s = s_u + lane;
            int r = s >> 4;
            int cs = (s & 15) ^ (r & 7);
            gload_lds16(QKV + kvbase + (size_t)r * QKVN + cs * 8, &Kb[0][(size_t)s_u * 8]);
        }
        u16x8 vr0 = *(const u16x8*)&QKV[kvbase + 512 + (size_t)lane * QKVN + (0 * 8 + wave) * 8];
        u16x8 vr1 = *(const u16x8*)&QKV[kvbase + 512 + (size_t)lane * QKVN + (1 * 8 + wave) * 8];
#pragma unroll
        for (int jj = 0; jj < 8; ++jj) {
            int d0 = wave * 8 + jj, d1 = (8 + wave) * 8 + jj;
            Vb[0][d0 * 64 + ((((lane >> 3) ^ jj) << 3) | (lane & 7))] = vr0[jj];
            Vb[0][d1 * 64 + ((((lane >> 3) ^ jj) << 3) | (lane & 7))] = vr1[jj];
        }
    }
    __syncthreads();

    for (int j = 0; j < 32; ++j) {
        const int cur = j & 1;
        const bool stage_next = (j < 31);
        u16x8 vn0, vn1;
        if (stage_next) {
            const size_t nb = kvbase + (size_t)(j + 1) * 64 * QKVN;
#pragma unroll
            for (int i = 0; i < 2; ++i) {
                int s_u = wave * 64 + 512 * i;
                int s = s_u + lane;
                int r = s >> 4;
                int cs = (s & 15) ^ (r & 7);
                gload_lds16(QKV + nb + (size_t)r * QKVN + cs * 8, &Kb[cur ^ 1][(size_t)s_u * 8]);
            }
            vn0 = *(const u16x8*)&QKV[nb + 512 + (size_t)lane * QKVN + (0 * 8 + wave) * 8];
            vn1 = *(const u16x8*)&QKV[nb + 512 + (size_t)lane * QKVN + (1 * 8 + wave) * 8];
        }
        if (j <= myqb) {
            f32x4 sacc[4] = {};
#pragma unroll
            for (int kc = 0; kc < 4; ++kc)
#pragma unroll
                for (int nt = 0; nt < 4; ++nt) {
                    int cs = ((kc * 4 + l4) ^ (l15 & 7));
                    bf16x8 kf = *(const bf16x8*)&Kb[cur][(nt * 16 + l15) * 128 + cs * 8];
                    sacc[nt] = __builtin_amdgcn_mfma_f32_16x16x32_bf16(qf[kc], kf, sacc[nt], 0, 0, 0);
                }
            if (j == myqb) {
#pragma unroll
                for (int nt = 0; nt < 4; ++nt)
#pragma unroll
                    for (int r = 0; r < 4; ++r)
                        if (nt * 16 + l15 > wl * 16 + l4 * 4 + r)
                            sacc[nt][r] = -1e30f;
            }
#pragma unroll
            for (int r = 0; r < 4; ++r) {
                float mx = fmaxf(fmaxf(sacc[0][r], sacc[1][r]), fmaxf(sacc[2][r], sacc[3][r]));
#pragma unroll
                for (int d = 1; d < 16; d <<= 1) mx = fmaxf(mx, __shfl_xor(mx, d, 64));
                float mnew = fmaxf(mrow[r], mx);
                float fs = __expf(mrow[r] - mnew);
                mrow[r] = mnew;
                float ps = 0.f;
#pragma unroll
                for (int nt = 0; nt < 4; ++nt) {
                    float pe = __expf(sacc[nt][r] - mnew);
                    sacc[nt][r] = pe;
                    ps += pe;
                }
#pragma unroll
                for (int d = 1; d < 16; d <<= 1) ps += __shfl_xor(ps, d, 64);
                lrow[r] = lrow[r] * fs + ps;
#pragma unroll
                for (int nt = 0; nt < 8; ++nt) oacc[nt][r] *= fs;
            }
#pragma unroll
            for (int nt = 0; nt < 4; ++nt)
#pragma unroll
                for (int r = 0; r < 4; ++r) {
                    int qrow = l4 * 4 + r;
                    int k = nt * 16 + l15;
                    Pl[wave][qrow * 64 + ((((k >> 3) ^ (qrow & 7)) << 3) | (k & 7))] = f2b(sacc[nt][r]);
                }
            bf16x8 pf0 = *(const bf16x8*)&Pl[wave][l15 * 64 + ((l4 ^ (l15 & 7)) << 3)];
            bf16x8 pf1 = *(const bf16x8*)&Pl[wave][l15 * 64 + (((4 + l4) ^ (l15 & 7)) << 3)];
#pragma unroll
            for (int nt = 0; nt < 8; ++nt) {
                int d = nt * 16 + l15;           // d&7 == l15&7
                bf16x8 v0 = *(const bf16x8*)&Vb[cur][d * 64 + ((l4 ^ (l15 & 7)) << 3)];
                bf16x8 v1 = *(const bf16x8*)&Vb[cur][d * 64 + (((4 + l4) ^ (l15 & 7)) << 3)];
                oacc[nt] = __builtin_amdgcn_mfma_f32_16x16x32_bf16(pf0, v0, oacc[nt], 0, 0, 0);
                oacc[nt] = __builtin_amdgcn_mfma_f32_16x16x32_bf16(pf1, v1, oacc[nt], 0, 0, 0);
            }
        }
        if (stage_next) {
#pragma unroll
            for (int jj = 0; jj < 8; ++jj) {
                int d0 = wave * 8 + jj, d1 = (8 + wave) * 8 + jj;
                Vb[cur ^ 1][d0 * 64 + ((((lane >> 3) ^ jj) << 3) | (lane & 7))] = vn0[jj];
                Vb[cur ^ 1][d1 * 64 + ((((lane >> 3) ^ jj) << 3) | (lane & 7))] = vn1[jj];
            }
        }
        __syncthreads();   // drains vmcnt (K gloads) + lgkmcnt (V writes); next iter ready
    }
#pragma unroll
    for (int nt = 0; nt < 8; ++nt)
#pragma unroll
        for (int r = 0; r < 4; ++r) {
            int qg = myqb * 64 + wl * 16 + l4 * 4 + r;
            O[(size_t)(b * Sv + qg) * 2048 + h * 128 + nt * 16 + l15] = f2b(oacc[nt][r] / lrow[r]);
        }
}

extern "C" void kernel_launch(void* const* d_in, const int* in_sizes, int n_in,
                              void* d_out, int out_size, void* d_ws, size_t ws_size,
                              hipStream_t stream) {
    const float* x   = (const float*)d_in[0];
    const float* fc  = (const float*)d_in[1];
    const int*   mod = (const int*)d_in[2];
    const float* wq  = (const float*)d_in[3];
    const float* wk  = (const float*)d_in[4];
    const float* wv  = (const float*)d_in[5];
    const float* wo  = (const float*)d_in[6];
    float* out = (float*)d_out;
    char* ws = (char*)d_ws;
    u16* Wqkv_t = (u16*)(ws);               // 2 x (3072 x 2048) bf16 = 25,165,824
    u16* Wo_t   = (u16*)(ws + 25165824);    // 2 x (2048 x 2048) bf16 = 16,777,216
    u16* Xg     = (u16*)(ws + 41943040);    // MAXROWS x 2048 bf16 = 17,301,504 (reused as Ag)
    u16* QKV    = (u16*)(ws + 59244544);    // 4096 x 3072 bf16 = 25,165,824
    int* fwd    = (int*)(ws + 84410368);    // 4096 ints
    int* inv    = (int*)(ws + 84426752);    // MAXROWS ints (+pad)
    int* hdr    = (int*)(ws + 84444160);    // small header
    u16* Ag     = Xg;                        // Xg dead after QKV GEMM
    u16* O      = (u16*)(ws);                // 4096 x 2048 bf16, aliases dead Wqkv_t

    transpose_cast<<<dim3(32, 32, 2), 256, 0, stream>>>(wq, Wqkv_t, 2048,
        (size_t)2048 * 2048, (size_t)3072 * 2048);
    transpose_cast<<<dim3(8, 32, 2),  256, 0, stream>>>(wk, Wqkv_t + (size_t)2048 * 2048, 512,
        (size_t)2048 * 512,  (size_t)3072 * 2048);
    transpose_cast<<<dim3(8, 32, 2),  256, 0, stream>>>(wv, Wqkv_t + (size_t)2560 * 2048, 512,
        (size_t)2048 * 512,  (size_t)3072 * 2048);
    transpose_cast<<<dim3(32, 32, 2), 256, 0, stream>>>(wo, Wo_t, 2048,
        (size_t)2048 * 2048, (size_t)2048 * 2048);
    scan_mod<<<1, 1024, 0, stream>>>(mod, fwd, inv, hdr);
    gather_cast<<<MAXROWS, 256, 0, stream>>>(x, inv, Xg);
    gemm_seg<u16><<<dim3(24, 33), 256, 0, stream>>>(Xg, Wqkv_t, QKV, inv, hdr, 3072, 3072);
    rope_kernel<<<20480, 256, 0, stream>>>(QKV, fc);
    // attn -> direct token-major O (R4-exact)
    attn_fwd<<<dim3(16, 16, 2), 512, 0, stream>>>(QKV, O);
    // compact reorder for out-proj A-operand
    gather_rows<<<MAXROWS, 256, 0, stream>>>(O, inv, Ag);
    gemm_seg<float><<<dim3(16, 33), 256, 0, stream>>>(Ag, Wo_t, out, inv, hdr, 2048, 2048);
}

// Round 8
// 303.319 us; speedup vs baseline: 1.1822x; 1.1795x over previous
//
#include <hip/hip_runtime.h>
#include <stdint.h>

typedef unsigned short u16;
typedef __bf16  bf16x8 __attribute__((ext_vector_type(8), may_alias));
typedef u16     u16x8  __attribute__((ext_vector_type(8), may_alias));
typedef float   f32x4  __attribute__((ext_vector_type(4)));
typedef float   f32x4u __attribute__((ext_vector_type(4), may_alias));

#define Bv   2
#define Sv   2048
#define Dv   2048
#define Hv   16
#define KVHv 4
#define HDv  128
#define Tv   (Bv*Sv)      // 4096 tokens
#define QKVN 3072         // 2048 Q + 512 K + 512 V
#define MAXROWS 4224      // 33 tiles of 128 (worst-case padded segments)

__device__ __forceinline__ float b2f(u16 u) {
    union { float f; uint32_t i; } x; x.i = ((uint32_t)u) << 16; return x.f;
}
__device__ __forceinline__ u16 f2b(float f) {
    union { float f; uint32_t u; } x; x.f = f;
    uint32_t r = x.u + 0x7fff + ((x.u >> 16) & 1);
    return (u16)(r >> 16);
}
// global -> LDS direct (16B per lane; LDS dest wave-uniform base, HW adds lane*16)
__device__ __forceinline__ void gload_lds16(const void* g, void* l) {
    __builtin_amdgcn_global_load_lds((__attribute__((address_space(1))) void*)(uintptr_t)g,
                                     (__attribute__((address_space(3))) void*)(uintptr_t)l,
                                     16, 0, 0);
}

// ---------- stable modality compaction: fwd[t]=compact pos, inv[pos]=t (or -1 pad) ----------
__global__ __launch_bounds__(1024) void scan_mod(const int* __restrict__ mod, int* __restrict__ fwd,
                                                 int* __restrict__ inv, int* __restrict__ hdr) {
    __shared__ int cnt[1024];
    const int tid = threadIdx.x;
    int m[4]; int c = 0;
#pragma unroll
    for (int e = 0; e < 4; ++e) { m[e] = mod[tid * 4 + e]; c += (m[e] == 0); }
    cnt[tid] = c;
    __syncthreads();
    for (int off = 1; off < 1024; off <<= 1) {
        int v = (tid >= off) ? cnt[tid - off] : 0;
        __syncthreads();
        cnt[tid] += v;
        __syncthreads();
    }
    const int c0 = cnt[1023];
    const int c0pad = (c0 + 127) & ~127;
    const int c1 = Tv - c0;
    const int total = c0pad + ((c1 + 127) & ~127);
    for (int p = tid; p < MAXROWS; p += 1024) inv[p] = -1;
    __syncthreads();
    const int ex0 = cnt[tid] - c;            // mod-0 tokens before this chunk
    int z = 0;
#pragma unroll
    for (int e = 0; e < 4; ++e) {
        int t = tid * 4 + e;
        int pos;
        if (m[e] == 0) { pos = ex0 + z; ++z; }
        else           { pos = c0pad + (t - (ex0 + z)); }
        fwd[t] = pos;
        inv[pos] = t;
    }
    if (tid == 0) { hdr[0] = total >> 7; hdr[1] = c0pad; hdr[2] = total; }
}

// ---------- gather + cast: Xg[pos] = bf16(x[inv[pos]]) or 0 ----------
__global__ void gather_cast(const float* __restrict__ x, const int* __restrict__ inv,
                            u16* __restrict__ Xg) {
    int v = blockIdx.x * 256 + threadIdx.x;
    int pos = v >> 8, c8 = (v & 255) * 8;
    int t = inv[pos];
    u16x8 val = {0, 0, 0, 0, 0, 0, 0, 0};
    if (t >= 0) {
        f32x4u a = *(const f32x4u*)&x[(size_t)t * Dv + c8];
        f32x4u b = *(const f32x4u*)&x[(size_t)t * Dv + c8 + 4];
#pragma unroll
        for (int j = 0; j < 4; ++j) { val[j] = f2b(a[j]); val[4 + j] = f2b(b[j]); }
    }
    *(u16x8*)&Xg[(size_t)pos * Dv + c8] = val;
}

// ---------- gather rows (bf16): Ag[pos] = O[inv[pos]] or 0 ----------
__global__ void gather_rows(const u16* __restrict__ O, const int* __restrict__ inv,
                            u16* __restrict__ Ag) {
    int pos = blockIdx.x;
    int c8 = threadIdx.x * 8;
    int t = inv[pos];
    u16x8 val = {0, 0, 0, 0, 0, 0, 0, 0};
    if (t >= 0) val = *(const u16x8*)&O[(size_t)t * 2048 + c8];
    *(u16x8*)&Ag[(size_t)pos * 2048 + c8] = val;
}

// ---------- transpose + cast f32->bf16, batched over modality (blockIdx.z) ----------
__global__ void transpose_cast(const float* __restrict__ in, u16* __restrict__ out, int C,
                               size_t inZ, size_t outZ) {
    in  += (size_t)blockIdx.z * inZ;
    out += (size_t)blockIdx.z * outZ;
    __shared__ u16 tile[64][72];
    const int tr = blockIdx.y * 64, tc = blockIdx.x * 64;
    const int tid = threadIdx.x;
#pragma unroll
    for (int i = 0; i < 4; ++i) {
        int s = tid + 256 * i;
        int r = s >> 4, c4 = (s & 15) * 4;
        f32x4u v = *(const f32x4u*)&in[(size_t)(tr + r) * C + tc + c4];
#pragma unroll
        for (int j = 0; j < 4; ++j) tile[r][c4 + j] = f2b(v[j]);
    }
    __syncthreads();
#pragma unroll
    for (int i = 0; i < 2; ++i) {
        int s = tid + 256 * i;
        int r = s >> 3, c8 = (s & 7) * 8;
        u16x8 v;
#pragma unroll
        for (int j = 0; j < 8; ++j) v[j] = tile[c8 + j][r];
        *(u16x8*)&out[(size_t)(tc + r) * 2048 + tr + c8] = v;
    }
}

// ---------- segmented GEMM: C[inv[row]] = A(total x 2048) * Wt_seg(Nfull x 2048)^T ----------
template <typename OutT>
__global__ __launch_bounds__(256) void gemm_seg(const u16* __restrict__ A,
                                                const u16* __restrict__ Bt,
                                                OutT* __restrict__ C,
                                                const int* __restrict__ inv,
                                                const int* __restrict__ hdr,
                                                int Nfull, int ldC) {
    const int total = hdr[2], c0pad = hdr[1];
    const int bm = blockIdx.y * 128;
    if (bm >= total) return;
    const u16* B = Bt + (size_t)((bm >= c0pad) ? 1 : 0) * Nfull * 2048;
    const int bn = blockIdx.x * 128;
    const int tid = threadIdx.x;
    const int wave = tid >> 6, lane = tid & 63;
    const int l15 = lane & 15, l4 = lane >> 4;
    const int wr = (wave >> 1) * 64, wc = (wave & 1) * 64;
    __shared__ u16 lA[2][128 * 64];
    __shared__ u16 lB[2][128 * 64];
    f32x4 acc[4][4] = {};
    auto STAGE = [&](int kt, int buf) {
#pragma unroll
        for (int i = 0; i < 4; ++i) {
            int s_u = wave * 64 + 256 * i;
            int s = s_u + lane;
            int r = s >> 3, k8 = (s & 7) * 8;
            gload_lds16(A + (size_t)(bm + r) * 2048 + kt * 64 + k8, &lA[buf][(size_t)s_u * 8]);
            gload_lds16(B + (size_t)(bn + r) * 2048 + kt * 64 + k8, &lB[buf][(size_t)s_u * 8]);
        }
    };
    STAGE(0, 0);
    __syncthreads();
    for (int kt = 0; kt < 32; ++kt) {
        const int cur = kt & 1;
        if (kt < 31) STAGE(kt + 1, cur ^ 1);
#pragma unroll
        for (int kc = 0; kc < 2; ++kc) {
            bf16x8 af[4], bfr[4];
#pragma unroll
            for (int i = 0; i < 4; ++i)
                af[i] = *(const bf16x8*)&lA[cur][(wr + i * 16 + l15) * 64 + kc * 32 + l4 * 8];
#pragma unroll
            for (int j = 0; j < 4; ++j)
                bfr[j] = *(const bf16x8*)&lB[cur][(wc + j * 16 + l15) * 64 + kc * 32 + l4 * 8];
#pragma unroll
            for (int i = 0; i < 4; ++i)
#pragma unroll
                for (int j = 0; j < 4; ++j)
                    acc[i][j] = __builtin_amdgcn_mfma_f32_16x16x32_bf16(af[i], bfr[j], acc[i][j], 0, 0, 0);
        }
        __syncthreads();
    }
    int tok[4][4];
#pragma unroll
    for (int i = 0; i < 4; ++i)
#pragma unroll
        for (int r = 0; r < 4; ++r)
            tok[i][r] = inv[bm + wr + i * 16 + l4 * 4 + r];
#pragma unroll
    for (int i = 0; i < 4; ++i)
#pragma unroll
        for (int j = 0; j < 4; ++j) {
            int col = bn + wc + j * 16 + l15;
#pragma unroll
            for (int r = 0; r < 4; ++r)
                if (tok[i][r] >= 0) {
                    if constexpr (sizeof(OutT) == 2) C[(size_t)tok[i][r] * ldC + col] = f2b(acc[i][j][r]);
                    else                             C[(size_t)tok[i][r] * ldC + col] = acc[i][j][r];
                }
        }
}

// ---------- RoPE in place on Q,K halves of QKV (bf16); freq_cis f32; folds 1/sqrt(HD) into Q ----------
__global__ void rope_kernel(u16* __restrict__ QKV, const float* __restrict__ fc) {
    int p = blockIdx.x * 256 + threadIdx.x;
    const int t = p / 1280;
    const int r = p - t * 1280;
    const int s = t & (Sv - 1);
    int col, d2; float scale;
    if (r < 1024) { col = 2 * r;                d2 = r & 63;  scale = 0.08838834764831845f; }
    else          { int rr = r - 1024; col = 2048 + 2 * rr; d2 = rr & 63; scale = 1.0f; }
    u16* ptr = QKV + (size_t)t * QKVN + col;
    float t0 = b2f(ptr[0]), t1 = b2f(ptr[1]);
    f32x4u f = *(const f32x4u*)&fc[((size_t)s * 64 + d2) * 4];   // [c, -s, s, c]
    ptr[0] = f2b((t0 * f[0] + t1 * f[1]) * scale);
    ptr[1] = f2b((t0 * f[2] + t1 * f[3]) * scale);
}

// ---------- causal GQA flash attention (paired q-tiles, 2-phase K/V pipeline) ----------
// SWAPPED QK^T: mfma(K, Q) -> S: col=q=l15, row=kv=l4*4+r, nt = kv-tile.
// Softmax per q-row is lane-local (in-lane trees) + 2 shfl_xor hops (d=16,32);
// fs/lrow redistributed to oacc's q=l4*4+r rows via 4 independent shfl.
__global__ __launch_bounds__(512) void attn_fwd(const u16* __restrict__ QKV, u16* __restrict__ O) {
    const int p = blockIdx.x;                 // pair id 0..15
    const int h = blockIdx.y, b = blockIdx.z;
    const int kvh = h >> 2;
    const int tid = threadIdx.x, wave = tid >> 6, lane = tid & 63;
    const int wgrp = wave >> 2, wl = wave & 3;
    const int l15 = lane & 15, l4 = lane >> 4;
    const int myqb = wgrp ? (31 - p) : p;     // this wave-group's q-tile
    __shared__ u16 Kb[2][64 * 128];
    __shared__ u16 Vb[2][128 * 64];
    __shared__ u16 Pl[8][16 * 64];

    bf16x8 qf[4];
    {
        const size_t qrow = (size_t)(b * Sv + myqb * 64 + wl * 16 + l15);
#pragma unroll
        for (int kc = 0; kc < 4; ++kc)
            qf[kc] = *(const bf16x8*)&QKV[qrow * QKVN + h * 128 + kc * 32 + l4 * 8];
    }
    f32x4 oacc[8] = {};
    float mrow = -1e30f;   // running max for q = l15 (replicated across l4 groups)
    float lrow = 0.f;      // running sum for q = l15

    const size_t kvbase = (size_t)b * Sv * QKVN + 2048 + kvh * 128;

    // ---- prologue: stage tile 0 into buffer 0 ----
    {
#pragma unroll
        for (int i = 0; i < 2; ++i) {
            int s_u = wave * 64 + 512 * i;
            int s = s_u + lane;
            int r = s >> 4;
            int cs = (s & 15) ^ (r & 7);
            gload_lds16(QKV + kvbase + (size_t)r * QKVN + cs * 8, &Kb[0][(size_t)s_u * 8]);
        }
        u16x8 vr0 = *(const u16x8*)&QKV[kvbase + 512 + (size_t)lane * QKVN + (0 * 8 + wave) * 8];
        u16x8 vr1 = *(const u16x8*)&QKV[kvbase + 512 + (size_t)lane * QKVN + (1 * 8 + wave) * 8];
#pragma unroll
        for (int jj = 0; jj < 8; ++jj) {
            int d0 = wave * 8 + jj, d1 = (8 + wave) * 8 + jj;
            Vb[0][d0 * 64 + ((((lane >> 3) ^ jj) << 3) | (lane & 7))] = vr0[jj];
            Vb[0][d1 * 64 + ((((lane >> 3) ^ jj) << 3) | (lane & 7))] = vr1[jj];
        }
    }
    __syncthreads();

    for (int j = 0; j < 32; ++j) {
        const int cur = j & 1;
        const bool stage_next = (j < 31);
        u16x8 vn0, vn1;
        if (stage_next) {
            const size_t nb = kvbase + (size_t)(j + 1) * 64 * QKVN;
#pragma unroll
            for (int i = 0; i < 2; ++i) {
                int s_u = wave * 64 + 512 * i;
                int s = s_u + lane;
                int r = s >> 4;
                int cs = (s & 15) ^ (r & 7);
                gload_lds16(QKV + nb + (size_t)r * QKVN + cs * 8, &Kb[cur ^ 1][(size_t)s_u * 8]);
            }
            vn0 = *(const u16x8*)&QKV[nb + 512 + (size_t)lane * QKVN + (0 * 8 + wave) * 8];
            vn1 = *(const u16x8*)&QKV[nb + 512 + (size_t)lane * QKVN + (1 * 8 + wave) * 8];
        }
        if (j <= myqb) {
            f32x4 sacc[4] = {};
            // S = K Q^T: A=K-frag, B=Q-frag (both lane-mappings unchanged)
#pragma unroll
            for (int kc = 0; kc < 4; ++kc)
#pragma unroll
                for (int nt = 0; nt < 4; ++nt) {
                    int cs = ((kc * 4 + l4) ^ (l15 & 7));
                    bf16x8 kf = *(const bf16x8*)&Kb[cur][(nt * 16 + l15) * 128 + cs * 8];
                    sacc[nt] = __builtin_amdgcn_mfma_f32_16x16x32_bf16(kf, qf[kc], sacc[nt], 0, 0, 0);
                }
            if (j == myqb) {
                // mask kv_local > q_local: kv = nt*16 + l4*4 + r, q = wl*16 + l15
#pragma unroll
                for (int nt = 0; nt < 4; ++nt)
#pragma unroll
                    for (int r = 0; r < 4; ++r)
                        if (nt * 16 + l4 * 4 + r > wl * 16 + l15)
                            sacc[nt][r] = -1e30f;
            }
            // ---- lane-local online softmax for q = l15 ----
            f32x4 mv = sacc[0];
#pragma unroll
            for (int nt = 1; nt < 4; ++nt)
#pragma unroll
                for (int r = 0; r < 4; ++r) mv[r] = fmaxf(mv[r], sacc[nt][r]);
            float mx = fmaxf(fmaxf(mv[0], mv[1]), fmaxf(mv[2], mv[3]));
            mx = fmaxf(mx, __shfl_xor(mx, 16, 64));
            mx = fmaxf(mx, __shfl_xor(mx, 32, 64));
            float mnew = fmaxf(mrow, mx);
            float fs = __expf(mrow - mnew);
            mrow = mnew;
            f32x4 pv = {0.f, 0.f, 0.f, 0.f};
#pragma unroll
            for (int nt = 0; nt < 4; ++nt)
#pragma unroll
                for (int r = 0; r < 4; ++r) {
                    float pe = __expf(sacc[nt][r] - mnew);
                    sacc[nt][r] = pe;
                    pv[r] += pe;
                }
            float ps = (pv[0] + pv[1]) + (pv[2] + pv[3]);
            ps += __shfl_xor(ps, 16, 64);
            ps += __shfl_xor(ps, 32, 64);
            lrow = lrow * fs + ps;
            // redistribute fs (keyed q=l15) to oacc rows (q=l4*4+r): lane q holds it
            float fsq[4];
#pragma unroll
            for (int r = 0; r < 4; ++r) fsq[r] = __shfl(fs, l4 * 4 + r, 64);
#pragma unroll
            for (int nt = 0; nt < 8; ++nt)
#pragma unroll
                for (int r = 0; r < 4; ++r) oacc[nt][r] *= fsq[r];
            // P -> per-wave LDS (swizzled): P[q=l15][kv=nt*16+l4*4+r]
#pragma unroll
            for (int nt = 0; nt < 4; ++nt)
#pragma unroll
                for (int r = 0; r < 4; ++r) {
                    int kv = nt * 16 + l4 * 4 + r;
                    Pl[wave][l15 * 64 + ((((kv >> 3) ^ (l15 & 7)) << 3) | (kv & 7))] = f2b(sacc[nt][r]);
                }
            bf16x8 pf0 = *(const bf16x8*)&Pl[wave][l15 * 64 + ((l4 ^ (l15 & 7)) << 3)];
            bf16x8 pf1 = *(const bf16x8*)&Pl[wave][l15 * 64 + (((4 + l4) ^ (l15 & 7)) << 3)];
#pragma unroll
            for (int nt = 0; nt < 8; ++nt) {
                int d = nt * 16 + l15;           // d&7 == l15&7
                bf16x8 v0 = *(const bf16x8*)&Vb[cur][d * 64 + ((l4 ^ (l15 & 7)) << 3)];
                bf16x8 v1 = *(const bf16x8*)&Vb[cur][d * 64 + (((4 + l4) ^ (l15 & 7)) << 3)];
                oacc[nt] = __builtin_amdgcn_mfma_f32_16x16x32_bf16(pf0, v0, oacc[nt], 0, 0, 0);
                oacc[nt] = __builtin_amdgcn_mfma_f32_16x16x32_bf16(pf1, v1, oacc[nt], 0, 0, 0);
            }
        }
        if (stage_next) {
#pragma unroll
            for (int jj = 0; jj < 8; ++jj) {
                int d0 = wave * 8 + jj, d1 = (8 + wave) * 8 + jj;
                Vb[cur ^ 1][d0 * 64 + ((((lane >> 3) ^ jj) << 3) | (lane & 7))] = vn0[jj];
                Vb[cur ^ 1][d1 * 64 + ((((lane >> 3) ^ jj) << 3) | (lane & 7))] = vn1[jj];
            }
        }
        __syncthreads();   // drains vmcnt (K gloads) + lgkmcnt (V writes); next iter ready
    }
    float lrq[4];
#pragma unroll
    for (int r = 0; r < 4; ++r) lrq[r] = __shfl(lrow, l4 * 4 + r, 64);
#pragma unroll
    for (int nt = 0; nt < 8; ++nt)
#pragma unroll
        for (int r = 0; r < 4; ++r) {
            int qg = myqb * 64 + wl * 16 + l4 * 4 + r;
            O[(size_t)(b * Sv + qg) * 2048 + h * 128 + nt * 16 + l15] = f2b(oacc[nt][r] / lrq[r]);
        }
}

extern "C" void kernel_launch(void* const* d_in, const int* in_sizes, int n_in,
                              void* d_out, int out_size, void* d_ws, size_t ws_size,
                              hipStream_t stream) {
    const float* x   = (const float*)d_in[0];
    const float* fc  = (const float*)d_in[1];
    const int*   mod = (const int*)d_in[2];
    const float* wq  = (const float*)d_in[3];
    const float* wk  = (const float*)d_in[4];
    const float* wv  = (const float*)d_in[5];
    const float* wo  = (const float*)d_in[6];
    float* out = (float*)d_out;
    char* ws = (char*)d_ws;
    u16* Wqkv_t = (u16*)(ws);               // 2 x (3072 x 2048) bf16 = 25,165,824
    u16* Wo_t   = (u16*)(ws + 25165824);    // 2 x (2048 x 2048) bf16 = 16,777,216
    u16* Xg     = (u16*)(ws + 41943040);    // MAXROWS x 2048 bf16 = 17,301,504 (reused as Ag)
    u16* QKV    = (u16*)(ws + 59244544);    // 4096 x 3072 bf16 = 25,165,824
    int* fwd    = (int*)(ws + 84410368);    // 4096 ints
    int* inv    = (int*)(ws + 84426752);    // MAXROWS ints (+pad)
    int* hdr    = (int*)(ws + 84444160);    // small header
    u16* Ag     = Xg;                        // Xg dead after QKV GEMM
    u16* O      = (u16*)(ws);                // 4096 x 2048 bf16, aliases dead Wqkv_t

    transpose_cast<<<dim3(32, 32, 2), 256, 0, stream>>>(wq, Wqkv_t, 2048,
        (size_t)2048 * 2048, (size_t)3072 * 2048);
    transpose_cast<<<dim3(8, 32, 2),  256, 0, stream>>>(wk, Wqkv_t + (size_t)2048 * 2048, 512,
        (size_t)2048 * 512,  (size_t)3072 * 2048);
    transpose_cast<<<dim3(8, 32, 2),  256, 0, stream>>>(wv, Wqkv_t + (size_t)2560 * 2048, 512,
        (size_t)2048 * 512,  (size_t)3072 * 2048);
    transpose_cast<<<dim3(32, 32, 2), 256, 0, stream>>>(wo, Wo_t, 2048,
        (size_t)2048 * 2048, (size_t)2048 * 2048);
    scan_mod<<<1, 1024, 0, stream>>>(mod, fwd, inv, hdr);
    gather_cast<<<MAXROWS, 256, 0, stream>>>(x, inv, Xg);
    gemm_seg<u16><<<dim3(24, 33), 256, 0, stream>>>(Xg, Wqkv_t, QKV, inv, hdr, 3072, 3072);
    rope_kernel<<<20480, 256, 0, stream>>>(QKV, fc);
    // attn -> direct token-major O (swapped-QK lane-local softmax)
    attn_fwd<<<dim3(16, 16, 2), 512, 0, stream>>>(QKV, O);
    // compact reorder for out-proj A-operand
    gather_rows<<<MAXROWS, 256, 0, stream>>>(O, inv, Ag);
    gemm_seg<float><<<dim3(16, 33), 256, 0, stream>>>(Ag, Wo_t, out, inv, hdr, 2048, 2048);
}

// Round 9
// 243.304 us; speedup vs baseline: 1.4738x; 1.2467x over previous
//
#include <hip/hip_runtime.h>
#include <stdint.h>

typedef unsigned short u16;
typedef __bf16  bf16x8 __attribute__((ext_vector_type(8), may_alias));
typedef u16     u16x8  __attribute__((ext_vector_type(8), may_alias));
typedef float   f32x4  __attribute__((ext_vector_type(4)));
typedef float   f32x4u __attribute__((ext_vector_type(4), may_alias));

#define Bv   2
#define Sv   2048
#define Dv   2048
#define Hv   16
#define KVHv 4
#define HDv  128
#define Tv   (Bv*Sv)      // 4096 tokens
#define QKVN 3072         // 2048 Q + 512 K + 512 V
#define MAXROWS 4352      // 17 tiles of 256 (worst-case padded segments)

__device__ __forceinline__ float b2f(u16 u) {
    union { float f; uint32_t i; } x; x.i = ((uint32_t)u) << 16; return x.f;
}
__device__ __forceinline__ u16 f2b(float f) {
    union { float f; uint32_t u; } x; x.f = f;
    uint32_t r = x.u + 0x7fff + ((x.u >> 16) & 1);
    return (u16)(r >> 16);
}
// global -> LDS direct (16B per lane; LDS dest wave-uniform base, HW adds lane*16)
__device__ __forceinline__ void gload_lds16(const void* g, void* l) {
    __builtin_amdgcn_global_load_lds((__attribute__((address_space(1))) void*)(uintptr_t)g,
                                     (__attribute__((address_space(3))) void*)(uintptr_t)l,
                                     16, 0, 0);
}

// ---------- stable modality compaction (segments padded to 256 rows) ----------
__global__ __launch_bounds__(1024) void scan_mod(const int* __restrict__ mod, int* __restrict__ fwd,
                                                 int* __restrict__ inv, int* __restrict__ hdr) {
    __shared__ int cnt[1024];
    const int tid = threadIdx.x;
    int m[4]; int c = 0;
#pragma unroll
    for (int e = 0; e < 4; ++e) { m[e] = mod[tid * 4 + e]; c += (m[e] == 0); }
    cnt[tid] = c;
    __syncthreads();
    for (int off = 1; off < 1024; off <<= 1) {
        int v = (tid >= off) ? cnt[tid - off] : 0;
        __syncthreads();
        cnt[tid] += v;
        __syncthreads();
    }
    const int c0 = cnt[1023];
    const int c0pad = (c0 + 255) & ~255;
    const int c1 = Tv - c0;
    const int total = c0pad + ((c1 + 255) & ~255);
    for (int p = tid; p < MAXROWS; p += 1024) inv[p] = -1;
    __syncthreads();
    const int ex0 = cnt[tid] - c;            // mod-0 tokens before this chunk
    int z = 0;
#pragma unroll
    for (int e = 0; e < 4; ++e) {
        int t = tid * 4 + e;
        int pos;
        if (m[e] == 0) { pos = ex0 + z; ++z; }
        else           { pos = c0pad + (t - (ex0 + z)); }
        fwd[t] = pos;
        inv[pos] = t;
    }
    if (tid == 0) { hdr[0] = total >> 8; hdr[1] = c0pad; hdr[2] = total; }
}

// ---------- gather + cast: Xg[pos] = bf16(x[inv[pos]]) or 0 ----------
__global__ void gather_cast(const float* __restrict__ x, const int* __restrict__ inv,
                            u16* __restrict__ Xg) {
    int v = blockIdx.x * 256 + threadIdx.x;
    int pos = v >> 8, c8 = (v & 255) * 8;
    int t = inv[pos];
    u16x8 val = {0, 0, 0, 0, 0, 0, 0, 0};
    if (t >= 0) {
        f32x4u a = *(const f32x4u*)&x[(size_t)t * Dv + c8];
        f32x4u b = *(const f32x4u*)&x[(size_t)t * Dv + c8 + 4];
#pragma unroll
        for (int j = 0; j < 4; ++j) { val[j] = f2b(a[j]); val[4 + j] = f2b(b[j]); }
    }
    *(u16x8*)&Xg[(size_t)pos * Dv + c8] = val;
}

// ---------- gather rows (bf16): Ag[pos] = O[inv[pos]] or 0 ----------
__global__ void gather_rows(const u16* __restrict__ O, const int* __restrict__ inv,
                            u16* __restrict__ Ag) {
    int pos = blockIdx.x;
    int c8 = threadIdx.x * 8;
    int t = inv[pos];
    u16x8 val = {0, 0, 0, 0, 0, 0, 0, 0};
    if (t >= 0) val = *(const u16x8*)&O[(size_t)t * 2048 + c8];
    *(u16x8*)&Ag[(size_t)pos * 2048 + c8] = val;
}

// ---------- transpose + cast f32->bf16, batched over modality (blockIdx.z) ----------
__global__ void transpose_cast(const float* __restrict__ in, u16* __restrict__ out, int C,
                               size_t inZ, size_t outZ) {
    in  += (size_t)blockIdx.z * inZ;
    out += (size_t)blockIdx.z * outZ;
    __shared__ u16 tile[64][72];
    const int tr = blockIdx.y * 64, tc = blockIdx.x * 64;
    const int tid = threadIdx.x;
#pragma unroll
    for (int i = 0; i < 4; ++i) {
        int s = tid + 256 * i;
        int r = s >> 4, c4 = (s & 15) * 4;
        f32x4u v = *(const f32x4u*)&in[(size_t)(tr + r) * C + tc + c4];
#pragma unroll
        for (int j = 0; j < 4; ++j) tile[r][c4 + j] = f2b(v[j]);
    }
    __syncthreads();
#pragma unroll
    for (int i = 0; i < 2; ++i) {
        int s = tid + 256 * i;
        int r = s >> 3, c8 = (s & 7) * 8;
        u16x8 v;
#pragma unroll
        for (int j = 0; j < 8; ++j) v[j] = tile[c8 + j][r];
        *(u16x8*)&out[(size_t)(tc + r) * 2048 + tr + c8] = v;
    }
}

__device__ __forceinline__ void store_c(u16* C, size_t idx, float v) { C[idx] = f2b(v); }
__device__ __forceinline__ void store_c(float* C, size_t idx, float v) { C[idx] = v; }

// ---------- 256x256 segmented GEMM, 8 waves, counted-vmcnt 4-phase pipeline ----------
// C[inv[row]] = A(total x 2048) @ Wt_seg(Nfull x 2048)^T.
// LDS per operand: [slot 2][half 2][128 rows][64 k] bf16, XOR-swizzle: 16B slot s at s^(row&7),
// staged via pre-swizzled global source (linear gload_lds dest).
// Stage order of tile kt+1 during kt's phases: ph0 B-half0, ph1 B-half1, ph2 A rows0-63 (both
// halves), ph3 A rows64-127. Publication: vmcnt(4)@ph1-end (A-b of kt), vmcnt(2)@ph3-end
// (B + A-a of kt+1); per-wave outstanding ledger verified for prologue/steady/last.
template <typename OutT>
__global__ __launch_bounds__(512, 2) void gemm256(const u16* __restrict__ A,
                                                  const u16* __restrict__ Bt,
                                                  OutT* __restrict__ C,
                                                  const int* __restrict__ inv,
                                                  const int* __restrict__ hdr,
                                                  int Nfull, int ldC) {
    const int total = hdr[2], c0pad = hdr[1];
    const int bm = blockIdx.y * 256;
    if (bm >= total) return;
    const u16* B = Bt + (size_t)((bm >= c0pad) ? 1 : 0) * Nfull * 2048;
    const int bn = blockIdx.x * 256;
    const int tid = threadIdx.x;
    const int wave = tid >> 6, lane = tid & 63;
    const int l15 = lane & 15, l4 = lane >> 4;
    const int wm = wave >> 2;                 // A-half owned by this wave
    const int wn = wave & 3;
    const int bhh = wn >> 1, brr = (wn & 1) * 64;   // B half + row offset within half
    const int rsw = l15 & 7;
    __shared__ u16 ldsA[2][2][128 * 64];
    __shared__ u16 ldsB[2][2][128 * 64];
    const int srow = tid >> 3;                // staging row within 64-row block
    const int ssw  = (tid & 7) ^ (srow & 7);  // pre-swizzled 16B slot
    const int wofs = wave * 8 * 64;           // wave-uniform LDS portion (8 rows x 64 elem)

    f32x4 acc[8][4] = {};

    auto stA = [&](int sl, int h, int jrb, int kt) {
        gload_lds16(A + (size_t)(bm + h * 128 + jrb * 64 + srow) * 2048 + kt * 64 + ssw * 8,
                    &ldsA[sl][h][jrb * 64 * 64 + wofs]);
    };
    auto stB = [&](int sl, int h, int jrb, int kt) {
        gload_lds16(B + (size_t)(bn + h * 128 + jrb * 64 + srow) * 2048 + kt * 64 + ssw * 8,
                    &ldsB[sl][h][jrb * 64 * 64 + wofs]);
    };

    // prologue: tile 0 into slot 0 (order: B,B,B,B, A-a,A-a, A-b,A-b)
    stB(0, 0, 0, 0); stB(0, 0, 1, 0); stB(0, 1, 0, 0); stB(0, 1, 1, 0);
    stA(0, 0, 0, 0); stA(0, 1, 0, 0); stA(0, 0, 1, 0); stA(0, 1, 1, 0);
    asm volatile("s_waitcnt vmcnt(2)" ::: "memory");
    __builtin_amdgcn_s_barrier();
    __builtin_amdgcn_sched_barrier(0);

    for (int kt = 0; kt < 32; ++kt) {
        const int s = kt & 1;
        const bool st = (kt < 31);
        // B-frags for the whole tile (published by prior ph3-end / prologue)
        bf16x8 bfr[4][2];
#pragma unroll
        for (int fj = 0; fj < 4; ++fj)
#pragma unroll
            for (int kc = 0; kc < 2; ++kc)
                bfr[fj][kc] = *(const bf16x8*)&ldsB[s][bhh][(brr + fj * 16 + l15) * 64 + ((kc * 4 + l4) ^ rsw) * 8];
#pragma unroll
        for (int q = 0; q < 4; ++q) {
            bf16x8 af[2][2];
#pragma unroll
            for (int fi = 0; fi < 2; ++fi)
#pragma unroll
                for (int kc = 0; kc < 2; ++kc)
                    af[fi][kc] = *(const bf16x8*)&ldsA[s][wm][(q * 32 + fi * 16 + l15) * 64 + ((kc * 4 + l4) ^ rsw) * 8];
            if (st) {
                if      (q == 0) { stB(s ^ 1, 0, 0, kt + 1); stB(s ^ 1, 0, 1, kt + 1); }
                else if (q == 1) { stB(s ^ 1, 1, 0, kt + 1); stB(s ^ 1, 1, 1, kt + 1); }
                else if (q == 2) { stA(s ^ 1, 0, 0, kt + 1); stA(s ^ 1, 1, 0, kt + 1); }
                else             { stA(s ^ 1, 0, 1, kt + 1); stA(s ^ 1, 1, 1, kt + 1); }
            }
            __builtin_amdgcn_s_setprio(1);
#pragma unroll
            for (int kc = 0; kc < 2; ++kc)
#pragma unroll
                for (int fi = 0; fi < 2; ++fi)
#pragma unroll
                    for (int fj = 0; fj < 4; ++fj)
                        acc[q * 2 + fi][fj] = __builtin_amdgcn_mfma_f32_16x16x32_bf16(
                            af[fi][kc], bfr[fj][kc], acc[q * 2 + fi][fj], 0, 0, 0);
            __builtin_amdgcn_s_setprio(0);
            if (q == 1) {
                if (st) asm volatile("s_waitcnt vmcnt(4)" ::: "memory");
                else    asm volatile("s_waitcnt vmcnt(0)" ::: "memory");
                __builtin_amdgcn_sched_barrier(0);
            }
            if (q == 3 && st) {
                asm volatile("s_waitcnt vmcnt(2)" ::: "memory");
                __builtin_amdgcn_sched_barrier(0);
            }
            __builtin_amdgcn_s_barrier();
            __builtin_amdgcn_sched_barrier(0);
        }
    }
    // epilogue: scatter rows token-major via inv
#pragma unroll
    for (int fi = 0; fi < 8; ++fi)
#pragma unroll
        for (int r = 0; r < 4; ++r) {
            int row = bm + wm * 128 + fi * 16 + l4 * 4 + r;
            int t = inv[row];
            if (t >= 0) {
#pragma unroll
                for (int fj = 0; fj < 4; ++fj) {
                    int col = bn + wn * 64 + fj * 16 + l15;
                    store_c(C, (size_t)t * ldC + col, acc[fi][fj][r]);
                }
            }
        }
}

// ---------- RoPE in place on Q,K halves of QKV (bf16); freq_cis f32; folds 1/sqrt(HD) into Q ----------
__global__ void rope_kernel(u16* __restrict__ QKV, const float* __restrict__ fc) {
    int p = blockIdx.x * 256 + threadIdx.x;
    const int t = p / 1280;
    const int r = p - t * 1280;
    const int s = t & (Sv - 1);
    int col, d2; float scale;
    if (r < 1024) { col = 2 * r;                d2 = r & 63;  scale = 0.08838834764831845f; }
    else          { int rr = r - 1024; col = 2048 + 2 * rr; d2 = rr & 63; scale = 1.0f; }
    u16* ptr = QKV + (size_t)t * QKVN + col;
    float t0 = b2f(ptr[0]), t1 = b2f(ptr[1]);
    f32x4u f = *(const f32x4u*)&fc[((size_t)s * 64 + d2) * 4];   // [c, -s, s, c]
    ptr[0] = f2b((t0 * f[0] + t1 * f[1]) * scale);
    ptr[1] = f2b((t0 * f[2] + t1 * f[3]) * scale);
}

// ---------- causal GQA flash attention (paired q-tiles, swapped-QK lane-local softmax) ----------
__global__ __launch_bounds__(512) void attn_fwd(const u16* __restrict__ QKV, u16* __restrict__ O) {
    const int p = blockIdx.x;                 // pair id 0..15
    const int h = blockIdx.y, b = blockIdx.z;
    const int kvh = h >> 2;
    const int tid = threadIdx.x, wave = tid >> 6, lane = tid & 63;
    const int wgrp = wave >> 2, wl = wave & 3;
    const int l15 = lane & 15, l4 = lane >> 4;
    const int myqb = wgrp ? (31 - p) : p;     // this wave-group's q-tile
    __shared__ u16 Kb[2][64 * 128];
    __shared__ u16 Vb[2][128 * 64];
    __shared__ u16 Pl[8][16 * 64];

    bf16x8 qf[4];
    {
        const size_t qrow = (size_t)(b * Sv + myqb * 64 + wl * 16 + l15);
#pragma unroll
        for (int kc = 0; kc < 4; ++kc)
            qf[kc] = *(const bf16x8*)&QKV[qrow * QKVN + h * 128 + kc * 32 + l4 * 8];
    }
    f32x4 oacc[8] = {};
    float mrow = -1e30f;
    float lrow = 0.f;

    const size_t kvbase = (size_t)b * Sv * QKVN + 2048 + kvh * 128;

    {
#pragma unroll
        for (int i = 0; i < 2; ++i) {
            int s_u = wave * 64 + 512 * i;
            int s = s_u + lane;
            int r = s >> 4;
            int cs = (s & 15) ^ (r & 7);
            gload_lds16(QKV + kvbase + (size_t)r * QKVN + cs * 8, &Kb[0][(size_t)s_u * 8]);
        }
        u16x8 vr0 = *(const u16x8*)&QKV[kvbase + 512 + (size_t)lane * QKVN + (0 * 8 + wave) * 8];
        u16x8 vr1 = *(const u16x8*)&QKV[kvbase + 512 + (size_t)lane * QKVN + (1 * 8 + wave) * 8];
#pragma unroll
        for (int jj = 0; jj < 8; ++jj) {
            int d0 = wave * 8 + jj, d1 = (8 + wave) * 8 + jj;
            Vb[0][d0 * 64 + ((((lane >> 3) ^ jj) << 3) | (lane & 7))] = vr0[jj];
            Vb[0][d1 * 64 + ((((lane >> 3) ^ jj) << 3) | (lane & 7))] = vr1[jj];
        }
    }
    __syncthreads();

    for (int j = 0; j < 32; ++j) {
        const int cur = j & 1;
        const bool stage_next = (j < 31);
        u16x8 vn0, vn1;
        if (stage_next) {
            const size_t nb = kvbase + (size_t)(j + 1) * 64 * QKVN;
#pragma unroll
            for (int i = 0; i < 2; ++i) {
                int s_u = wave * 64 + 512 * i;
                int s = s_u + lane;
                int r = s >> 4;
                int cs = (s & 15) ^ (r & 7);
                gload_lds16(QKV + nb + (size_t)r * QKVN + cs * 8, &Kb[cur ^ 1][(size_t)s_u * 8]);
            }
            vn0 = *(const u16x8*)&QKV[nb + 512 + (size_t)lane * QKVN + (0 * 8 + wave) * 8];
            vn1 = *(const u16x8*)&QKV[nb + 512 + (size_t)lane * QKVN + (1 * 8 + wave) * 8];
        }
        if (j <= myqb) {
            f32x4 sacc[4] = {};
#pragma unroll
            for (int kc = 0; kc < 4; ++kc)
#pragma unroll
                for (int nt = 0; nt < 4; ++nt) {
                    int cs = ((kc * 4 + l4) ^ (l15 & 7));
                    bf16x8 kf = *(const bf16x8*)&Kb[cur][(nt * 16 + l15) * 128 + cs * 8];
                    sacc[nt] = __builtin_amdgcn_mfma_f32_16x16x32_bf16(kf, qf[kc], sacc[nt], 0, 0, 0);
                }
            if (j == myqb) {
#pragma unroll
                for (int nt = 0; nt < 4; ++nt)
#pragma unroll
                    for (int r = 0; r < 4; ++r)
                        if (nt * 16 + l4 * 4 + r > wl * 16 + l15)
                            sacc[nt][r] = -1e30f;
            }
            f32x4 mv = sacc[0];
#pragma unroll
            for (int nt = 1; nt < 4; ++nt)
#pragma unroll
                for (int r = 0; r < 4; ++r) mv[r] = fmaxf(mv[r], sacc[nt][r]);
            float mx = fmaxf(fmaxf(mv[0], mv[1]), fmaxf(mv[2], mv[3]));
            mx = fmaxf(mx, __shfl_xor(mx, 16, 64));
            mx = fmaxf(mx, __shfl_xor(mx, 32, 64));
            float mnew = fmaxf(mrow, mx);
            float fs = __expf(mrow - mnew);
            mrow = mnew;
            f32x4 pv = {0.f, 0.f, 0.f, 0.f};
#pragma unroll
            for (int nt = 0; nt < 4; ++nt)
#pragma unroll
                for (int r = 0; r < 4; ++r) {
                    float pe = __expf(sacc[nt][r] - mnew);
                    sacc[nt][r] = pe;
                    pv[r] += pe;
                }
            float ps = (pv[0] + pv[1]) + (pv[2] + pv[3]);
            ps += __shfl_xor(ps, 16, 64);
            ps += __shfl_xor(ps, 32, 64);
            lrow = lrow * fs + ps;
            float fsq[4];
#pragma unroll
            for (int r = 0; r < 4; ++r) fsq[r] = __shfl(fs, l4 * 4 + r, 64);
#pragma unroll
            for (int nt = 0; nt < 8; ++nt)
#pragma unroll
                for (int r = 0; r < 4; ++r) oacc[nt][r] *= fsq[r];
#pragma unroll
            for (int nt = 0; nt < 4; ++nt)
#pragma unroll
                for (int r = 0; r < 4; ++r) {
                    int kv = nt * 16 + l4 * 4 + r;
                    Pl[wave][l15 * 64 + ((((kv >> 3) ^ (l15 & 7)) << 3) | (kv & 7))] = f2b(sacc[nt][r]);
                }
            bf16x8 pf0 = *(const bf16x8*)&Pl[wave][l15 * 64 + ((l4 ^ (l15 & 7)) << 3)];
            bf16x8 pf1 = *(const bf16x8*)&Pl[wave][l15 * 64 + (((4 + l4) ^ (l15 & 7)) << 3)];
#pragma unroll
            for (int nt = 0; nt < 8; ++nt) {
                int d = nt * 16 + l15;
                bf16x8 v0 = *(const bf16x8*)&Vb[cur][d * 64 + ((l4 ^ (l15 & 7)) << 3)];
                bf16x8 v1 = *(const bf16x8*)&Vb[cur][d * 64 + (((4 + l4) ^ (l15 & 7)) << 3)];
                oacc[nt] = __builtin_amdgcn_mfma_f32_16x16x32_bf16(pf0, v0, oacc[nt], 0, 0, 0);
                oacc[nt] = __builtin_amdgcn_mfma_f32_16x16x32_bf16(pf1, v1, oacc[nt], 0, 0, 0);
            }
        }
        if (stage_next) {
#pragma unroll
            for (int jj = 0; jj < 8; ++jj) {
                int d0 = wave * 8 + jj, d1 = (8 + wave) * 8 + jj;
                Vb[cur ^ 1][d0 * 64 + ((((lane >> 3) ^ jj) << 3) | (lane & 7))] = vn0[jj];
                Vb[cur ^ 1][d1 * 64 + ((((lane >> 3) ^ jj) << 3) | (lane & 7))] = vn1[jj];
            }
        }
        __syncthreads();
    }
    float lrq[4];
#pragma unroll
    for (int r = 0; r < 4; ++r) lrq[r] = __shfl(lrow, l4 * 4 + r, 64);
#pragma unroll
    for (int nt = 0; nt < 8; ++nt)
#pragma unroll
        for (int r = 0; r < 4; ++r) {
            int qg = myqb * 64 + wl * 16 + l4 * 4 + r;
            O[(size_t)(b * Sv + qg) * 2048 + h * 128 + nt * 16 + l15] = f2b(oacc[nt][r] / lrq[r]);
        }
}

extern "C" void kernel_launch(void* const* d_in, const int* in_sizes, int n_in,
                              void* d_out, int out_size, void* d_ws, size_t ws_size,
                              hipStream_t stream) {
    const float* x   = (const float*)d_in[0];
    const float* fc  = (const float*)d_in[1];
    const int*   mod = (const int*)d_in[2];
    const float* wq  = (const float*)d_in[3];
    const float* wk  = (const float*)d_in[4];
    const float* wv  = (const float*)d_in[5];
    const float* wo  = (const float*)d_in[6];
    float* out = (float*)d_out;
    char* ws = (char*)d_ws;
    u16* Wqkv_t = (u16*)(ws);               // 2 x (3072 x 2048) bf16 = 25,165,824
    u16* Wo_t   = (u16*)(ws + 25165824);    // 2 x (2048 x 2048) bf16 = 16,777,216
    u16* Xg     = (u16*)(ws + 41943040);    // MAXROWS x 2048 bf16 = 17,825,792 (reused as Ag)
    u16* QKV    = (u16*)(ws + 59768832);    // 4096 x 3072 bf16 = 25,165,824
    int* fwd    = (int*)(ws + 84934656);    // 4096 ints
    int* inv    = (int*)(ws + 84951040);    // MAXROWS ints
    int* hdr    = (int*)(ws + 84968448);    // small header
    u16* Ag     = Xg;                        // Xg dead after QKV GEMM
    u16* O      = (u16*)(ws);                // 4096 x 2048 bf16, aliases dead Wqkv_t

    transpose_cast<<<dim3(32, 32, 2), 256, 0, stream>>>(wq, Wqkv_t, 2048,
        (size_t)2048 * 2048, (size_t)3072 * 2048);
    transpose_cast<<<dim3(8, 32, 2),  256, 0, stream>>>(wk, Wqkv_t + (size_t)2048 * 2048, 512,
        (size_t)2048 * 512,  (size_t)3072 * 2048);
    transpose_cast<<<dim3(8, 32, 2),  256, 0, stream>>>(wv, Wqkv_t + (size_t)2560 * 2048, 512,
        (size_t)2048 * 512,  (size_t)3072 * 2048);
    transpose_cast<<<dim3(32, 32, 2), 256, 0, stream>>>(wo, Wo_t, 2048,
        (size_t)2048 * 2048, (size_t)2048 * 2048);
    scan_mod<<<1, 1024, 0, stream>>>(mod, fwd, inv, hdr);
    gather_cast<<<MAXROWS, 256, 0, stream>>>(x, inv, Xg);
    gemm256<u16><<<dim3(12, 17), 512, 0, stream>>>(Xg, Wqkv_t, QKV, inv, hdr, 3072, 3072);
    rope_kernel<<<20480, 256, 0, stream>>>(QKV, fc);
    attn_fwd<<<dim3(16, 16, 2), 512, 0, stream>>>(QKV, O);
    gather_rows<<<MAXROWS, 256, 0, stream>>>(O, inv, Ag);
    gemm256<float><<<dim3(8, 17), 512, 0, stream>>>(Ag, Wo_t, out, inv, hdr, 2048, 2048);
}

// Round 11
// 230.871 us; speedup vs baseline: 1.5531x; 1.0539x over previous
//
#include <hip/hip_runtime.h>
#include <stdint.h>

typedef unsigned short u16;
typedef __bf16  bf16x8 __attribute__((ext_vector_type(8), may_alias));
typedef u16     u16x8  __attribute__((ext_vector_type(8), may_alias));
typedef float   f32x4  __attribute__((ext_vector_type(4)));
typedef float   f32x4u __attribute__((ext_vector_type(4), may_alias));

#define Bv   2
#define Sv   2048
#define Dv   2048
#define Hv   16
#define KVHv 4
#define HDv  128
#define Tv   (Bv*Sv)      // 4096 tokens
#define QKVN 3072         // 2048 Q + 512 K + 512 V
#define MAXROWS 4352      // 17 tiles of 256 (worst-case padded segments)

__device__ __forceinline__ float b2f(u16 u) {
    union { float f; uint32_t i; } x; x.i = ((uint32_t)u) << 16; return x.f;
}
__device__ __forceinline__ u16 f2b(float f) {
    union { float f; uint32_t u; } x; x.f = f;
    uint32_t r = x.u + 0x7fff + ((x.u >> 16) & 1);
    return (u16)(r >> 16);
}
// global -> LDS direct (16B per lane; LDS dest wave-uniform base, HW adds lane*16)
__device__ __forceinline__ void gload_lds16(const void* g, void* l) {
    __builtin_amdgcn_global_load_lds((__attribute__((address_space(1))) void*)(uintptr_t)g,
                                     (__attribute__((address_space(3))) void*)(uintptr_t)l,
                                     16, 0, 0);
}

// ---------- stable modality compaction (segments padded to 256 rows) ----------
__global__ __launch_bounds__(1024) void scan_mod(const int* __restrict__ mod, int* __restrict__ fwd,
                                                 int* __restrict__ inv, int* __restrict__ hdr) {
    __shared__ int cnt[1024];
    const int tid = threadIdx.x;
    int m[4]; int c = 0;
#pragma unroll
    for (int e = 0; e < 4; ++e) { m[e] = mod[tid * 4 + e]; c += (m[e] == 0); }
    cnt[tid] = c;
    __syncthreads();
    for (int off = 1; off < 1024; off <<= 1) {
        int v = (tid >= off) ? cnt[tid - off] : 0;
        __syncthreads();
        cnt[tid] += v;
        __syncthreads();
    }
    const int c0 = cnt[1023];
    const int c0pad = (c0 + 255) & ~255;
    const int c1 = Tv - c0;
    const int total = c0pad + ((c1 + 255) & ~255);
    for (int p = tid; p < MAXROWS; p += 1024) inv[p] = -1;
    __syncthreads();
    const int ex0 = cnt[tid] - c;            // mod-0 tokens before this chunk
    int z = 0;
#pragma unroll
    for (int e = 0; e < 4; ++e) {
        int t = tid * 4 + e;
        int pos;
        if (m[e] == 0) { pos = ex0 + z; ++z; }
        else           { pos = c0pad + (t - (ex0 + z)); }
        fwd[t] = pos;
        inv[pos] = t;
    }
    if (tid == 0) { hdr[0] = total >> 8; hdr[1] = c0pad; hdr[2] = total; }
}

// ---------- gather + cast: Xg[pos] = bf16(x[inv[pos]]) or 0 ----------
__global__ void gather_cast(const float* __restrict__ x, const int* __restrict__ inv,
                            u16* __restrict__ Xg) {
    int v = blockIdx.x * 256 + threadIdx.x;
    int pos = v >> 8, c8 = (v & 255) * 8;
    int t = inv[pos];
    u16x8 val = {0, 0, 0, 0, 0, 0, 0, 0};
    if (t >= 0) {
        f32x4u a = *(const f32x4u*)&x[(size_t)t * Dv + c8];
        f32x4u b = *(const f32x4u*)&x[(size_t)t * Dv + c8 + 4];
#pragma unroll
        for (int j = 0; j < 4; ++j) { val[j] = f2b(a[j]); val[4 + j] = f2b(b[j]); }
    }
    *(u16x8*)&Xg[(size_t)pos * Dv + c8] = val;
}

// ---------- transpose + cast f32->bf16, batched over modality (blockIdx.z) ----------
__global__ void transpose_cast(const float* __restrict__ in, u16* __restrict__ out, int C,
                               size_t inZ, size_t outZ) {
    in  += (size_t)blockIdx.z * inZ;
    out += (size_t)blockIdx.z * outZ;
    __shared__ u16 tile[64][72];
    const int tr = blockIdx.y * 64, tc = blockIdx.x * 64;
    const int tid = threadIdx.x;
#pragma unroll
    for (int i = 0; i < 4; ++i) {
        int s = tid + 256 * i;
        int r = s >> 4, c4 = (s & 15) * 4;
        f32x4u v = *(const f32x4u*)&in[(size_t)(tr + r) * C + tc + c4];
#pragma unroll
        for (int j = 0; j < 4; ++j) tile[r][c4 + j] = f2b(v[j]);
    }
    __syncthreads();
#pragma unroll
    for (int i = 0; i < 2; ++i) {
        int s = tid + 256 * i;
        int r = s >> 3, c8 = (s & 7) * 8;
        u16x8 v;
#pragma unroll
        for (int j = 0; j < 8; ++j) v[j] = tile[c8 + j][r];
        *(u16x8*)&out[(size_t)(tc + r) * 2048 + tr + c8] = v;
    }
}

__device__ __forceinline__ void store_c(u16* C, size_t idx, float v) { C[idx] = f2b(v); }
__device__ __forceinline__ void store_c(float* C, size_t idx, float v) { C[idx] = v; }

// ---------- 256x256 segmented GEMM, 8 waves, counted-vmcnt 4-phase pipeline ----------
template <typename OutT>
__global__ __launch_bounds__(512, 2) void gemm256(const u16* __restrict__ A,
                                                  const u16* __restrict__ Bt,
                                                  OutT* __restrict__ C,
                                                  const int* __restrict__ inv,
                                                  const int* __restrict__ hdr,
                                                  int Nfull, int ldC) {
    const int total = hdr[2], c0pad = hdr[1];
    const int bm = blockIdx.y * 256;
    if (bm >= total) return;
    const u16* B = Bt + (size_t)((bm >= c0pad) ? 1 : 0) * Nfull * 2048;
    const int bn = blockIdx.x * 256;
    const int tid = threadIdx.x;
    const int wave = tid >> 6, lane = tid & 63;
    const int l15 = lane & 15, l4 = lane >> 4;
    const int wm = wave >> 2;
    const int wn = wave & 3;
    const int bhh = wn >> 1, brr = (wn & 1) * 64;
    const int rsw = l15 & 7;
    __shared__ u16 ldsA[2][2][128 * 64];
    __shared__ u16 ldsB[2][2][128 * 64];
    const int srow = tid >> 3;
    const int ssw  = (tid & 7) ^ (srow & 7);
    const int wofs = wave * 8 * 64;

    f32x4 acc[8][4] = {};

    auto stA = [&](int sl, int h, int jrb, int kt) {
        gload_lds16(A + (size_t)(bm + h * 128 + jrb * 64 + srow) * 2048 + kt * 64 + ssw * 8,
                    &ldsA[sl][h][jrb * 64 * 64 + wofs]);
    };
    auto stB = [&](int sl, int h, int jrb, int kt) {
        gload_lds16(B + (size_t)(bn + h * 128 + jrb * 64 + srow) * 2048 + kt * 64 + ssw * 8,
                    &ldsB[sl][h][jrb * 64 * 64 + wofs]);
    };

    stB(0, 0, 0, 0); stB(0, 0, 1, 0); stB(0, 1, 0, 0); stB(0, 1, 1, 0);
    stA(0, 0, 0, 0); stA(0, 1, 0, 0); stA(0, 0, 1, 0); stA(0, 1, 1, 0);
    asm volatile("s_waitcnt vmcnt(2)" ::: "memory");
    __builtin_amdgcn_s_barrier();
    __builtin_amdgcn_sched_barrier(0);

    for (int kt = 0; kt < 32; ++kt) {
        const int s = kt & 1;
        const bool st = (kt < 31);
        bf16x8 bfr[4][2];
#pragma unroll
        for (int fj = 0; fj < 4; ++fj)
#pragma unroll
            for (int kc = 0; kc < 2; ++kc)
                bfr[fj][kc] = *(const bf16x8*)&ldsB[s][bhh][(brr + fj * 16 + l15) * 64 + ((kc * 4 + l4) ^ rsw) * 8];
#pragma unroll
        for (int q = 0; q < 4; ++q) {
            bf16x8 af[2][2];
#pragma unroll
            for (int fi = 0; fi < 2; ++fi)
#pragma unroll
                for (int kc = 0; kc < 2; ++kc)
                    af[fi][kc] = *(const bf16x8*)&ldsA[s][wm][(q * 32 + fi * 16 + l15) * 64 + ((kc * 4 + l4) ^ rsw) * 8];
            if (st) {
                if      (q == 0) { stB(s ^ 1, 0, 0, kt + 1); stB(s ^ 1, 0, 1, kt + 1); }
                else if (q == 1) { stB(s ^ 1, 1, 0, kt + 1); stB(s ^ 1, 1, 1, kt + 1); }
                else if (q == 2) { stA(s ^ 1, 0, 0, kt + 1); stA(s ^ 1, 1, 0, kt + 1); }
                else             { stA(s ^ 1, 0, 1, kt + 1); stA(s ^ 1, 1, 1, kt + 1); }
            }
            __builtin_amdgcn_s_setprio(1);
#pragma unroll
            for (int kc = 0; kc < 2; ++kc)
#pragma unroll
                for (int fi = 0; fi < 2; ++fi)
#pragma unroll
                    for (int fj = 0; fj < 4; ++fj)
                        acc[q * 2 + fi][fj] = __builtin_amdgcn_mfma_f32_16x16x32_bf16(
                            af[fi][kc], bfr[fj][kc], acc[q * 2 + fi][fj], 0, 0, 0);
            __builtin_amdgcn_s_setprio(0);
            if (q == 1) {
                if (st) asm volatile("s_waitcnt vmcnt(4)" ::: "memory");
                else    asm volatile("s_waitcnt vmcnt(0)" ::: "memory");
                __builtin_amdgcn_sched_barrier(0);
            }
            if (q == 3 && st) {
                asm volatile("s_waitcnt vmcnt(2)" ::: "memory");
                __builtin_amdgcn_sched_barrier(0);
            }
            __builtin_amdgcn_s_barrier();
            __builtin_amdgcn_sched_barrier(0);
        }
    }
#pragma unroll
    for (int fi = 0; fi < 8; ++fi)
#pragma unroll
        for (int r = 0; r < 4; ++r) {
            int row = bm + wm * 128 + fi * 16 + l4 * 4 + r;
            int t = inv[row];
            if (t >= 0) {
#pragma unroll
                for (int fj = 0; fj < 4; ++fj) {
                    int col = bn + wn * 64 + fj * 16 + l15;
                    store_c(C, (size_t)t * ldC + col, acc[fi][fj][r]);
                }
            }
        }
}

// ---------- RoPE in place; folds (1/sqrt(HD))*log2(e) into Q (exp2-domain softmax) ----------
__global__ void rope_kernel(u16* __restrict__ QKV, const float* __restrict__ fc) {
    int p = blockIdx.x * 256 + threadIdx.x;
    const int t = p / 1280;
    const int r = p - t * 1280;
    const int s = t & (Sv - 1);
    int col, d2; float scale;
    if (r < 1024) { col = 2 * r;                d2 = r & 63;  scale = 0.12751742f; }  // rsqrt(128)*log2e
    else          { int rr = r - 1024; col = 2048 + 2 * rr; d2 = rr & 63; scale = 1.0f; }
    u16* ptr = QKV + (size_t)t * QKVN + col;
    float t0 = b2f(ptr[0]), t1 = b2f(ptr[1]);
    f32x4u f = *(const f32x4u*)&fc[((size_t)s * 64 + d2) * 4];   // [c, -s, s, c]
    ptr[0] = f2b((t0 * f[0] + t1 * f[1]) * scale);
    ptr[1] = f2b((t0 * f[2] + t1 * f[3]) * scale);
}

// ---------- causal GQA flash attention ----------
// Swapped QK (q=l15 end-to-end) + PERMUTED K rows in LDS so P lands in PV B-frag order:
// LDS K row p holds global kv row kv'(p) = (p&32)|((p&12)<<1)|((p&16)>>2)|(p&3).
// Then sacc[nt][r] = P[q=l15][kv=(nt>>1)*32 + l4*8 + (nt&1)*4 + r] and the PV B-fragments
// are just 8x v_cvt_pk_bf16_f32 (no LDS roundtrip, no cross-lane). PV = mfma(V^T, P^T):
// output O^T (col=q), transposed once via per-wave LDS epilogue. exp2-domain softmax.
// Output written COMPACT at row fwd[token] (scatter-write measured free, R7).
// LDS buffers addressed by inline offset arithmetic (pointer-array init of LDS fails to compile).
__global__ __launch_bounds__(512) void attn_fwd(const u16* __restrict__ QKV, u16* __restrict__ Ag,
                                                const int* __restrict__ fwd) {
    const int p = blockIdx.x;                 // pair id 0..15
    const int h = blockIdx.y, b = blockIdx.z;
    const int kvh = h >> 2;
    const int tid = threadIdx.x, wave = tid >> 6, lane = tid & 63;
    const int wgrp = wave >> 2, wl = wave & 3;
    const int l15 = lane & 15, l4 = lane >> 4;
    const int myqb = wgrp ? (31 - p) : p;
    __shared__ u16 smem[32768];               // 64KB: K dbuf @0/@8192, V dbuf @16384/@24576

    bf16x8 qf[4];
    {
        const size_t qrow = (size_t)(b * Sv + myqb * 64 + wl * 16 + l15);
#pragma unroll
        for (int kc = 0; kc < 4; ++kc)
            qf[kc] = *(const bf16x8*)&QKV[qrow * QKVN + h * 128 + kc * 32 + l4 * 8];
    }
    f32x4 oacc[8] = {};
    float mrow = -1e30f;   // running max (log2 domain) for q = l15
    float lrow = 0.f;

    const size_t kvbase = (size_t)b * Sv * QKVN + 2048 + kvh * 128;

    // ---- prologue: stage tile 0 ----
    {
#pragma unroll
        for (int i = 0; i < 2; ++i) {
            int s_u = wave * 64 + 512 * i;
            int s = s_u + lane;
            int r = s >> 4;                                   // LDS row
            int kvsrc = (r & 32) | ((r & 12) << 1) | ((r & 16) >> 2) | (r & 3);
            int cs = (s & 15) ^ (r & 7);
            gload_lds16(QKV + kvbase + (size_t)kvsrc * QKVN + cs * 8, &smem[(size_t)s_u * 8]);
        }
        u16x8 vr0 = *(const u16x8*)&QKV[kvbase + 512 + (size_t)lane * QKVN + (0 * 8 + wave) * 8];
        u16x8 vr1 = *(const u16x8*)&QKV[kvbase + 512 + (size_t)lane * QKVN + (1 * 8 + wave) * 8];
#pragma unroll
        for (int jj = 0; jj < 8; ++jj) {
            int d0 = wave * 8 + jj, d1 = (8 + wave) * 8 + jj;
            smem[16384 + d0 * 64 + ((((lane >> 3) ^ jj) << 3) | (lane & 7))] = vr0[jj];
            smem[16384 + d1 * 64 + ((((lane >> 3) ^ jj) << 3) | (lane & 7))] = vr1[jj];
        }
    }
    __syncthreads();

    for (int j = 0; j < 32; ++j) {
        const int cur = j & 1;
        const bool stage_next = (j < 31);
        u16* Kcur = smem + cur * 8192;
        u16* Knxt = smem + (cur ^ 1) * 8192;
        u16* Vcur = smem + 16384 + cur * 8192;
        u16* Vnxt = smem + 16384 + (cur ^ 1) * 8192;
        u16x8 vn0, vn1;
        if (stage_next) {
            const size_t nb = kvbase + (size_t)(j + 1) * 64 * QKVN;
#pragma unroll
            for (int i = 0; i < 2; ++i) {
                int s_u = wave * 64 + 512 * i;
                int s = s_u + lane;
                int r = s >> 4;
                int kvsrc = (r & 32) | ((r & 12) << 1) | ((r & 16) >> 2) | (r & 3);
                int cs = (s & 15) ^ (r & 7);
                gload_lds16(QKV + nb + (size_t)kvsrc * QKVN + cs * 8, &Knxt[(size_t)s_u * 8]);
            }
            vn0 = *(const u16x8*)&QKV[nb + 512 + (size_t)lane * QKVN + (0 * 8 + wave) * 8];
            vn1 = *(const u16x8*)&QKV[nb + 512 + (size_t)lane * QKVN + (1 * 8 + wave) * 8];
        }
        if (j <= myqb) {
            f32x4 sacc[4] = {};
#pragma unroll
            for (int kc = 0; kc < 4; ++kc)
#pragma unroll
                for (int nt = 0; nt < 4; ++nt) {
                    int cs = ((kc * 4 + l4) ^ (l15 & 7));
                    bf16x8 kf = *(const bf16x8*)&Kcur[(nt * 16 + l15) * 128 + cs * 8];
                    sacc[nt] = __builtin_amdgcn_mfma_f32_16x16x32_bf16(kf, qf[kc], sacc[nt], 0, 0, 0);
                }
            if (j == myqb) {
                // actual kv for sacc[nt][r] = (nt>>1)*32 + l4*8 + (nt&1)*4 + r
#pragma unroll
                for (int nt = 0; nt < 4; ++nt)
#pragma unroll
                    for (int r = 0; r < 4; ++r)
                        if ((nt >> 1) * 32 + l4 * 8 + (nt & 1) * 4 + r > wl * 16 + l15)
                            sacc[nt][r] = -1e30f;
            }
            // ---- lane-local online softmax (log2 domain) for q = l15 ----
            f32x4 mv = sacc[0];
#pragma unroll
            for (int nt = 1; nt < 4; ++nt)
#pragma unroll
                for (int r = 0; r < 4; ++r) mv[r] = fmaxf(mv[r], sacc[nt][r]);
            float mx = fmaxf(fmaxf(mv[0], mv[1]), fmaxf(mv[2], mv[3]));
            mx = fmaxf(mx, __shfl_xor(mx, 16, 64));
            mx = fmaxf(mx, __shfl_xor(mx, 32, 64));
            float mnew = fmaxf(mrow, mx);
            float fs = exp2f(mrow - mnew);
            mrow = mnew;
            f32x4 pv = {0.f, 0.f, 0.f, 0.f};
#pragma unroll
            for (int nt = 0; nt < 4; ++nt)
#pragma unroll
                for (int r = 0; r < 4; ++r) {
                    float pe = exp2f(sacc[nt][r] - mnew);
                    sacc[nt][r] = pe;
                    pv[r] += pe;
                }
            float ps = (pv[0] + pv[1]) + (pv[2] + pv[3]);
            ps += __shfl_xor(ps, 16, 64);
            ps += __shfl_xor(ps, 32, 64);
            lrow = lrow * fs + ps;
#pragma unroll
            for (int nt = 0; nt < 8; ++nt)
#pragma unroll
                for (int r = 0; r < 4; ++r) oacc[nt][r] *= fs;
            // ---- P fragments in-register: 8x cvt_pk, zero cross-lane ----
            union { uint32_t w[4]; bf16x8 v; } pb0u, pb1u;
#pragma unroll
            for (int nt = 0; nt < 2; ++nt) {
                asm("v_cvt_pk_bf16_f32 %0, %1, %2" : "=v"(pb0u.w[nt * 2])     : "v"(sacc[nt][0]), "v"(sacc[nt][1]));
                asm("v_cvt_pk_bf16_f32 %0, %1, %2" : "=v"(pb0u.w[nt * 2 + 1]) : "v"(sacc[nt][2]), "v"(sacc[nt][3]));
                asm("v_cvt_pk_bf16_f32 %0, %1, %2" : "=v"(pb1u.w[nt * 2])     : "v"(sacc[nt + 2][0]), "v"(sacc[nt + 2][1]));
                asm("v_cvt_pk_bf16_f32 %0, %1, %2" : "=v"(pb1u.w[nt * 2 + 1]) : "v"(sacc[nt + 2][2]), "v"(sacc[nt + 2][3]));
            }
            bf16x8 pb0 = pb0u.v, pb1 = pb1u.v;
            // ---- PV: O^T += V^T * P^T (A = V^T frags, B = P frags) ----
#pragma unroll
            for (int nt = 0; nt < 8; ++nt) {
                int d = nt * 16 + l15;           // d&7 == l15&7
                bf16x8 v0 = *(const bf16x8*)&Vcur[d * 64 + ((l4 ^ (l15 & 7)) << 3)];
                bf16x8 v1 = *(const bf16x8*)&Vcur[d * 64 + (((4 + l4) ^ (l15 & 7)) << 3)];
                oacc[nt] = __builtin_amdgcn_mfma_f32_16x16x32_bf16(v0, pb0, oacc[nt], 0, 0, 0);
                oacc[nt] = __builtin_amdgcn_mfma_f32_16x16x32_bf16(v1, pb1, oacc[nt], 0, 0, 0);
            }
        }
        if (stage_next) {
#pragma unroll
            for (int jj = 0; jj < 8; ++jj) {
                int d0 = wave * 8 + jj, d1 = (8 + wave) * 8 + jj;
                Vnxt[d0 * 64 + ((((lane >> 3) ^ jj) << 3) | (lane & 7))] = vn0[jj];
                Vnxt[d1 * 64 + ((((lane >> 3) ^ jj) << 3) | (lane & 7))] = vn1[jj];
            }
        }
        __syncthreads();
    }
    // ---- epilogue: transpose O^T -> token-major via per-wave LDS (K/V buffers dead) ----
    {
        u16* epi = smem + wave * (16 * 136);   // [16 q][128 d + 8 pad]
        float rinv = 1.0f / lrow;              // per lane q=l15
#pragma unroll
        for (int nt = 0; nt < 8; ++nt)
#pragma unroll
            for (int r = 0; r < 4; ++r)
                epi[l15 * 136 + nt * 16 + l4 * 4 + r] = f2b(oacc[nt][r] * rinv);
        const int q = lane >> 2;
        const int rowmap = fwd[b * Sv + myqb * 64 + wl * 16 + q];
#pragma unroll
        for (int it = 0; it < 4; ++it) {
            int dv = (lane & 3) + it * 4;
            u16x8 v = *(const u16x8*)&epi[q * 136 + dv * 8];
            *(u16x8*)&Ag[(size_t)rowmap * 2048 + h * 128 + dv * 8] = v;
        }
    }
}

extern "C" void kernel_launch(void* const* d_in, const int* in_sizes, int n_in,
                              void* d_out, int out_size, void* d_ws, size_t ws_size,
                              hipStream_t stream) {
    const float* x   = (const float*)d_in[0];
    const float* fc  = (const float*)d_in[1];
    const int*   mod = (const int*)d_in[2];
    const float* wq  = (const float*)d_in[3];
    const float* wk  = (const float*)d_in[4];
    const float* wv  = (const float*)d_in[5];
    const float* wo  = (const float*)d_in[6];
    float* out = (float*)d_out;
    char* ws = (char*)d_ws;
    u16* Wqkv_t = (u16*)(ws);               // 2 x (3072 x 2048) bf16 = 25,165,824
    u16* Wo_t   = (u16*)(ws + 25165824);    // 2 x (2048 x 2048) bf16 = 16,777,216
    u16* Xg     = (u16*)(ws + 41943040);    // MAXROWS x 2048 bf16 = 17,825,792 (reused as Ag)
    u16* QKV    = (u16*)(ws + 59768832);    // 4096 x 3072 bf16 = 25,165,824
    int* fwd    = (int*)(ws + 84934656);    // 4096 ints
    int* inv    = (int*)(ws + 84951040);    // MAXROWS ints
    int* hdr    = (int*)(ws + 84968448);    // small header
    u16* Ag     = Xg;                        // Xg dead after QKV GEMM; pads stay zero from gather_cast

    transpose_cast<<<dim3(32, 32, 2), 256, 0, stream>>>(wq, Wqkv_t, 2048,
        (size_t)2048 * 2048, (size_t)3072 * 2048);
    transpose_cast<<<dim3(8, 32, 2),  256, 0, stream>>>(wk, Wqkv_t + (size_t)2048 * 2048, 512,
        (size_t)2048 * 512,  (size_t)3072 * 2048);
    transpose_cast<<<dim3(8, 32, 2),  256, 0, stream>>>(wv, Wqkv_t + (size_t)2560 * 2048, 512,
        (size_t)2048 * 512,  (size_t)3072 * 2048);
    transpose_cast<<<dim3(32, 32, 2), 256, 0, stream>>>(wo, Wo_t, 2048,
        (size_t)2048 * 2048, (size_t)2048 * 2048);
    scan_mod<<<1, 1024, 0, stream>>>(mod, fwd, inv, hdr);
    gather_cast<<<MAXROWS, 256, 0, stream>>>(x, inv, Xg);
    gemm256<u16><<<dim3(12, 17), 512, 0, stream>>>(Xg, Wqkv_t, QKV, inv, hdr, 3072, 3072);
    rope_kernel<<<20480, 256, 0, stream>>>(QKV, fc);
    attn_fwd<<<dim3(16, 16, 2), 512, 0, stream>>>(QKV, Ag, fwd);
    gemm256<float><<<dim3(8, 17), 512, 0, stream>>>(Ag, Wo_t, out, inv, hdr, 2048, 2048);
}